// Round 3
// baseline (4334.237 us; speedup 1.0000x reference)
//
#include <hip/hip_runtime.h>
#include <hip/hip_bf16.h>

using bf16 = __hip_bfloat16;

// ---------- helpers ----------
static __device__ __forceinline__ float toF(float x) { return x; }
static __device__ __forceinline__ float toF(bf16 x) { return __bfloat162float(x); }
static __device__ __forceinline__ void storeC(float* p, float v) { *p = v; }
static __device__ __forceinline__ void storeC(bf16* p, float v) { *p = __float2bfloat16(v); }

// ---------------------------------------------------------------------------
// Generic batched tiled GEMMs, fp32 accumulate. 64x64 tile, 256 thr, 4x4/thr.
// Batch: z -> (z/zdiv, z%zdiv) with separate hi/lo pointer strides per operand.
// gemm_nt: C[m,n] = sum_k A[m*lda+k] * B[n*ldb+k]      (k contiguous)
// gemm_tn: C[m,n] = sum_k A[k*lda+m] * B[k*ldb+n]      (m/n contiguous)
// All M,N multiples of 64, K multiple of 32 (true for every call here).
// ---------------------------------------------------------------------------
template <typename TA, typename TB, typename TC>
__global__ __launch_bounds__(256) void gemm_nt(
    const TA* __restrict__ A0, const TB* __restrict__ B0, TC* __restrict__ C0,
    int K, int lda, int ldb, int ldc, int zdiv,
    long sAhi, long sAlo, long sBhi, long sBlo, long sChi, long sClo)
{
    __shared__ float As[32][64];
    __shared__ float Bs[32][64];
    const int z = blockIdx.z;
    const TA* A = A0 + (long)(z / zdiv) * sAhi + (long)(z % zdiv) * sAlo;
    const TB* B = B0 + (long)(z / zdiv) * sBhi + (long)(z % zdiv) * sBlo;
    TC*       C = C0 + (long)(z / zdiv) * sChi + (long)(z % zdiv) * sClo;
    const int m0 = blockIdx.y * 64, n0 = blockIdx.x * 64;
    const int t = threadIdx.x;
    const int tn = t & 15, tm = t >> 4;
    const int lr = t >> 2, ks = (t & 3) * 8;   // loader: row lr (0..63), k-seg of 8
    float acc[4][4] = {};
    for (int k0 = 0; k0 < K; k0 += 32) {
        const TA* ap = A + (long)(m0 + lr) * lda + (k0 + ks);
        const TB* bp = B + (long)(n0 + lr) * ldb + (k0 + ks);
#pragma unroll
        for (int i = 0; i < 8; ++i) As[ks + i][lr] = toF(ap[i]);
#pragma unroll
        for (int i = 0; i < 8; ++i) Bs[ks + i][lr] = toF(bp[i]);
        __syncthreads();
#pragma unroll 8
        for (int kk = 0; kk < 32; ++kk) {
            float4 av = *reinterpret_cast<const float4*>(&As[kk][tm << 2]);
            float4 bv = *reinterpret_cast<const float4*>(&Bs[kk][tn << 2]);
            float a[4] = {av.x, av.y, av.z, av.w};
            float b[4] = {bv.x, bv.y, bv.z, bv.w};
#pragma unroll
            for (int i = 0; i < 4; ++i)
#pragma unroll
                for (int j = 0; j < 4; ++j) acc[i][j] += a[i] * b[j];
        }
        __syncthreads();
    }
#pragma unroll
    for (int i = 0; i < 4; ++i) {
        long row = m0 + (tm << 2) + i;
#pragma unroll
        for (int j = 0; j < 4; ++j)
            storeC(&C[row * (long)ldc + (n0 + (tn << 2) + j)], acc[i][j]);
    }
}

template <typename TA, typename TB, typename TC>
__global__ __launch_bounds__(256) void gemm_tn(
    const TA* __restrict__ A0, const TB* __restrict__ B0, TC* __restrict__ C0,
    int K, int lda, int ldb, int ldc, int zdiv,
    long sAhi, long sAlo, long sBhi, long sBlo, long sChi, long sClo)
{
    __shared__ float As[32][64];
    __shared__ float Bs[32][64];
    const int z = blockIdx.z;
    const TA* A = A0 + (long)(z / zdiv) * sAhi + (long)(z % zdiv) * sAlo;
    const TB* B = B0 + (long)(z / zdiv) * sBhi + (long)(z % zdiv) * sBlo;
    TC*       C = C0 + (long)(z / zdiv) * sChi + (long)(z % zdiv) * sClo;
    const int m0 = blockIdx.y * 64, n0 = blockIdx.x * 64;
    const int t = threadIdx.x;
    const int tn = t & 15, tm = t >> 4;
    const int lm = t & 63, ks = (t >> 6) * 8;  // loader: col lm (0..63), k-seg of 8
    float acc[4][4] = {};
    for (int k0 = 0; k0 < K; k0 += 32) {
        const TA* ap = A + (long)(k0 + ks) * lda + (m0 + lm);
        const TB* bp = B + (long)(k0 + ks) * ldb + (n0 + lm);
#pragma unroll
        for (int i = 0; i < 8; ++i) As[ks + i][lm] = toF(ap[(long)i * lda]);
#pragma unroll
        for (int i = 0; i < 8; ++i) Bs[ks + i][lm] = toF(bp[(long)i * ldb]);
        __syncthreads();
#pragma unroll 8
        for (int kk = 0; kk < 32; ++kk) {
            float4 av = *reinterpret_cast<const float4*>(&As[kk][tm << 2]);
            float4 bv = *reinterpret_cast<const float4*>(&Bs[kk][tn << 2]);
            float a[4] = {av.x, av.y, av.z, av.w};
            float b[4] = {bv.x, bv.y, bv.z, bv.w};
#pragma unroll
            for (int i = 0; i < 4; ++i)
#pragma unroll
                for (int j = 0; j < 4; ++j) acc[i][j] += a[i] * b[j];
        }
        __syncthreads();
    }
#pragma unroll
    for (int i = 0; i < 4; ++i) {
        long row = m0 + (tm << 2) + i;
#pragma unroll
        for (int j = 0; j < 4; ++j)
            storeC(&C[row * (long)ldc + (n0 + (tn << 2) + j)], acc[i][j]);
    }
}

// ---------- small kernels ----------
// wo_u_r[j][h*128+c] = wo_u[j][c*8+h]   (128 x 1024)
__global__ __launch_bounds__(256) void reorder_wo(const float* __restrict__ wo, float* __restrict__ wor)
{
    int i = blockIdx.x * 256 + threadIdx.x;   // 131072
    int j = i >> 10, col = i & 1023;
    int h = col >> 7, c = col & 127;
    wor[i] = wo[j * 1024 + c * 8 + h];
}

__global__ __launch_bounds__(64) void zero8(float* p)
{
    if (threadIdx.x < 8) p[threadIdx.x] = 0.f;
}

// mean/rstd per (b,h) over 16384 elems of attn_u
__global__ __launch_bounds__(256) void stats_bh(const float* __restrict__ x, float* __restrict__ stats)
{
    const float* p = x + (long)blockIdx.x * 16384;
    float s1 = 0.f, s2 = 0.f;
    for (int i = threadIdx.x; i < 16384; i += 256) { float v = p[i]; s1 += v; s2 += v * v; }
    __shared__ float r1[256], r2[256];
    int t = threadIdx.x;
    r1[t] = s1; r2[t] = s2; __syncthreads();
    for (int o = 128; o > 0; o >>= 1) {
        if (t < o) { r1[t] += r1[t + o]; r2[t] += r2[t + o]; }
        __syncthreads();
    }
    if (t == 0) {
        float mu = r1[0] * (1.f / 16384.f);
        float var = r2[0] * (1.f / 16384.f) - mu * mu;
        stats[blockIdx.x * 2] = mu;
        stats[blockIdx.x * 2 + 1] = rsqrtf(var + 1e-5f);
    }
}

// partial sums per b over 1024*4096 elems of attn2 (atomic into red[b*2..])
__global__ __launch_bounds__(256) void stats_big(const float* __restrict__ x, float* __restrict__ red)
{
    const float* p = x + (long)blockIdx.y * 4194304 + (long)blockIdx.x * 65536;
    float s1 = 0.f, s2 = 0.f;
    for (int i = threadIdx.x; i < 65536; i += 256) { float v = p[i]; s1 += v; s2 += v * v; }
    __shared__ float r1[256], r2[256];
    int t = threadIdx.x;
    r1[t] = s1; r2[t] = s2; __syncthreads();
    for (int o = 128; o > 0; o >>= 1) {
        if (t < o) { r1[t] += r1[t + o]; r2[t] += r2[t + o]; }
        __syncthreads();
    }
    if (t == 0) {
        atomicAdd(&red[blockIdx.y * 2], r1[0]);
        atomicAdd(&red[blockIdx.y * 2 + 1], r2[0]);
    }
}

// in-place: row = (b*8+h)*128 + c ; normalize by stats[bh], softmax over 128
__global__ __launch_bounds__(128) void softmax_row128(float* __restrict__ attn, const float* __restrict__ stats)
{
    const int row = blockIdx.x;
    const int bh = row >> 7;
    const float mu = stats[bh * 2], rs = stats[bh * 2 + 1];
    float* p = attn + (long)row * 128;
    const int t = threadIdx.x;
    float x = (p[t] - mu) * rs;
    float m = x;
#pragma unroll
    for (int o = 32; o > 0; o >>= 1) m = fmaxf(m, __shfl_xor(m, o));
    __shared__ float sm[2], ss[2];
    if ((t & 63) == 0) sm[t >> 6] = m;
    __syncthreads();
    m = fmaxf(sm[0], sm[1]);
    float e = expf(x - m);
    float s = e;
#pragma unroll
    for (int o = 32; o > 0; o >>= 1) s += __shfl_xor(s, o);
    if ((t & 63) == 0) ss[t >> 6] = s;
    __syncthreads();
    s = ss[0] + ss[1];
    p[t] = e / s;
}

// in-place: row = b*1024 + c ; normalize by red[b] (sums), softmax over 4096
__global__ __launch_bounds__(256) void softmax_row4096(float* __restrict__ attn2, const float* __restrict__ red)
{
    const int row = blockIdx.x;
    const int b = row >> 10;
    const float inv = 1.f / 4194304.f;
    float mu = red[b * 2] * inv;
    float var = red[b * 2 + 1] * inv - mu * mu;
    float rs = rsqrtf(var + 1e-5f);
    float* p = attn2 + (long)row * 4096;
    const int t = threadIdx.x;
    float v[16];
    float mx = -3.0e38f;
#pragma unroll
    for (int i = 0; i < 16; ++i) { float u = (p[i * 256 + t] - mu) * rs; v[i] = u; mx = fmaxf(mx, u); }
#pragma unroll
    for (int o = 32; o > 0; o >>= 1) mx = fmaxf(mx, __shfl_xor(mx, o));
    __shared__ float sm[4], ss[4];
    if ((t & 63) == 0) sm[t >> 6] = mx;
    __syncthreads();
    mx = fmaxf(fmaxf(sm[0], sm[1]), fmaxf(sm[2], sm[3]));
    float s = 0.f;
#pragma unroll
    for (int i = 0; i < 16; ++i) { v[i] = expf(v[i] - mx); s += v[i]; }
#pragma unroll
    for (int o = 32; o > 0; o >>= 1) s += __shfl_xor(s, o);
    if ((t & 63) == 0) ss[t >> 6] = s;
    __syncthreads();
    s = ss[0] + ss[1] + ss[2] + ss[3];
    float r = 1.f / s;
#pragma unroll
    for (int i = 0; i < 16; ++i) p[i * 256 + t] = v[i] * r;
}

// ---------------------------------------------------------------------------
extern "C" void kernel_launch(void* const* d_in, const int* in_sizes, int n_in,
                              void* d_out, int out_size, void* d_ws, size_t ws_size,
                              hipStream_t stream)
{
    const float* emb   = (const float*)d_in[0];
    const float* wq_uu = (const float*)d_in[1];
    const float* wk_uu = (const float*)d_in[2];
    const float* wv_uu = (const float*)d_in[3];
    const float* wq_lu = (const float*)d_in[4];
    const float* wk_lu = (const float*)d_in[5];
    const float* wv_lu = (const float*)d_in[6];
    const float* wo_u  = (const float*)d_in[7];
    const float* wo_l  = (const float*)d_in[8];
    float* out = (float*)d_out;               // reference output dtype is FLOAT32

    // ---- workspace (aliased slots, ~168 MB total) ----
    const long SLOT = 16777216;               // 16384*1024 elements
    bf16*  slotA  = (bf16*)d_ws;              // Qu -> ctxU -> V2
    bf16*  slotB  = slotA + SLOT;             // Ku -> Ql  -> ctx2
    bf16*  slotC  = slotB + SLOT;             // Vu -> K2
    float* attn2  = (float*)(slotC + SLOT);   // 16.7M floats (lower logits)
    float* attnU  = attn2;                    // aliased: 524288 floats, dead before attn2 written
    float* woUr   = attn2 + SLOT;             // 131072 floats
    float* statsU = woUr + 131072;            // 32*2
    float* red2   = statsU + 64;              // 4*2

    const float* emb_l = emb;                 // 4 x 4096 x 128
    const float* emb_u = emb + 2097152;       // 4 x 4096 x 128

    dim3 blk(256);

    // wo_u reorder: [j][c*8+h] -> [j][h*128+c]
    reorder_wo<<<dim3(512), blk, 0, stream>>>(wo_u, woUr);

    // ---- upper path ----
    // Qu/Ku: [b*n][1024] bf16
    gemm_nt<float, float, bf16><<<dim3(16, 256, 1), blk, 0, stream>>>(
        emb_u, wq_uu, slotA, 128, 128, 128, 1024, 1, 0, 0, 0, 0, 0, 0);
    gemm_nt<float, float, bf16><<<dim3(16, 256, 1), blk, 0, stream>>>(
        emb_u, wk_uu, slotB, 128, 128, 128, 1024, 1, 0, 0, 0, 0, 0, 0);

    // attnU: per z=(b*8+h): S[c,d] = sum_n Q[n,hc+c] K[n,hc+d]  (128x128, K=4096)
    gemm_tn<bf16, bf16, float><<<dim3(2, 2, 32), blk, 0, stream>>>(
        slotA, slotB, attnU, 4096, 1024, 1024, 128,
        8, 4194304, 128, 4194304, 128, 131072, 16384);

    stats_bh<<<dim3(32), blk, 0, stream>>>(attnU, statsU);
    softmax_row128<<<dim3(4096), dim3(128), 0, stream>>>(attnU, statsU);

    // Vu
    gemm_nt<float, float, bf16><<<dim3(16, 256, 1), blk, 0, stream>>>(
        emb_u, wv_uu, slotC, 128, 128, 128, 1024, 1, 0, 0, 0, 0, 0, 0);

    // ctxU (bf16, into slotA): per z=(b,h): C[n,c] = sum_d V[n,hc+d] sim[c,d]
    gemm_nt<bf16, float, bf16><<<dim3(2, 64, 32), blk, 0, stream>>>(
        slotC, attnU, slotA, 128, 1024, 128, 1024,
        8, 4194304, 128, 131072, 16384, 4194304, 128);

    // O_u = ctxU @ woUr^T -> out rows [4..8)  (float out)
    gemm_nt<bf16, float, float><<<dim3(2, 256, 1), blk, 0, stream>>>(
        slotA, woUr, out + 2097152L, 1024, 1024, 1024, 128, 1, 0, 0, 0, 0, 0, 0);

    // ---- lower path ----
    // Ql: [b*n][1024] bf16 (into slotB)
    gemm_nt<float, float, bf16><<<dim3(16, 256, 1), blk, 0, stream>>>(
        emb_l, wq_lu, slotB, 128, 128, 128, 1024, 1, 0, 0, 0, 0, 0, 0);

    // K2: [n][bp*1024+o] bf16 (into slotC) via z=bp batched C-write
    gemm_nt<float, float, bf16><<<dim3(16, 64, 4), blk, 0, stream>>>(
        emb_u, wk_lu, slotC, 128, 128, 128, 4096,
        4, 0, 524288, 0, 0, 0, 1024);

    // attn2: per z=b: S2[c,d] = sum_n Ql[b][n][c] * K2[n][d]  (1024x4096, K=4096)
    gemm_tn<bf16, bf16, float><<<dim3(64, 16, 4), blk, 0, stream>>>(
        slotB, slotC, attn2, 4096, 1024, 4096, 4096,
        4, 0, 4194304, 0, 0, 0, 4194304);

    zero8<<<dim3(1), dim3(64), 0, stream>>>(red2);
    stats_big<<<dim3(64, 4), blk, 0, stream>>>(attn2, red2);
    softmax_row4096<<<dim3(4096), blk, 0, stream>>>(attn2, red2);

    // V2: [n][bp*1024+o] bf16 (into slotA)
    gemm_nt<float, float, bf16><<<dim3(16, 64, 4), blk, 0, stream>>>(
        emb_u, wv_lu, slotA, 128, 128, 128, 4096,
        4, 0, 524288, 0, 0, 0, 1024);

    // ctx2 (bf16, into slotB): per z=b: C[n,c] = sum_d V2[n,d] * sim2[b][c,d]  (K=4096)
    gemm_nt<bf16, float, bf16><<<dim3(16, 64, 4), blk, 0, stream>>>(
        slotA, attn2, slotB, 4096, 4096, 4096, 1024,
        4, 0, 0, 0, 4194304, 0, 4194304);

    // O_l = ctx2 @ wo_l^T -> out rows [0..4)  (float out)
    gemm_nt<bf16, float, float><<<dim3(2, 256, 1), blk, 0, stream>>>(
        slotB, wo_l, out, 1024, 1024, 1024, 128, 1, 0, 0, 0, 0, 0, 0);
}

// Round 4
// 751.333 us; speedup vs baseline: 5.7687x; 5.7687x over previous
//
#include <hip/hip_runtime.h>
#include <hip/hip_bf16.h>

using bf16 = __hip_bfloat16;
typedef __attribute__((ext_vector_type(8))) short bf16x8;
typedef __attribute__((ext_vector_type(4))) float f32x4;

// ---------- store helpers ----------
static __device__ __forceinline__ void storeC(float* p, float v) { *p = v; }
static __device__ __forceinline__ void storeC(bf16* p, float v) { *p = __float2bfloat16(v); }

// ---------- async global->LDS (16B per lane, wave-uniform LDS base) ----------
static __device__ __forceinline__ void gl2lds16(const bf16* g, bf16* l)
{
    __builtin_amdgcn_global_load_lds(
        (const __attribute__((address_space(1))) unsigned int*)g,
        (__attribute__((address_space(3))) unsigned int*)l, 16, 0, 0);
}

// stage a 128x32 bf16 tile (global row-major, ld elems) into LDS [128][32]
// wave w stages rows [w*32, w*32+32); lane i -> row base+ (i>>2), k (i&3)*8
static __device__ __forceinline__ void stage_tile(const bf16* gtile, int ld, bf16* ltile, int w, int lane)
{
    const bf16* g0 = gtile + (long)(w * 32 + (lane >> 2)) * ld + ((lane & 3) << 3);
    gl2lds16(g0, ltile + (w * 32) * 32);
    gl2lds16(g0 + (long)16 * ld, ltile + (w * 32 + 16) * 32);
}

// ---------------------------------------------------------------------------
// MFMA NT GEMM: C[m,n] = sum_k A[m*lda+k] * B[n*ldb+k], A/B bf16, fp32 accum.
// 128x128 tile, BK=32, 256 thr = 4 waves (2x2), wave = 64x64 via 4x4 16x16x32.
// M,N multiples of 128; K multiple of 32. Batched over z like round-3 kernels.
// ---------------------------------------------------------------------------
template <typename TC>
__global__ __launch_bounds__(256) void gemm_mfma_nt(
    const bf16* __restrict__ A0, const bf16* __restrict__ B0, TC* __restrict__ C0,
    int K, int lda, int ldb, int ldc, int zdiv,
    long sAhi, long sAlo, long sBhi, long sBlo, long sChi, long sClo)
{
    __shared__ bf16 As[2][4096];
    __shared__ bf16 Bs[2][4096];
    const int z = blockIdx.z;
    const bf16* A = A0 + (long)(z / zdiv) * sAhi + (long)(z % zdiv) * sAlo + (long)blockIdx.y * 128 * lda;
    const bf16* B = B0 + (long)(z / zdiv) * sBhi + (long)(z % zdiv) * sBlo + (long)blockIdx.x * 128 * ldb;
    TC*       C = C0 + (long)(z / zdiv) * sChi + (long)(z % zdiv) * sClo;

    const int t = threadIdx.x, lane = t & 63, w = t >> 6;
    const int wm = w >> 1, wn = w & 1;

    f32x4 acc[4][4] = {};

    stage_tile(A, lda, &As[0][0], w, lane);
    stage_tile(B, ldb, &Bs[0][0], w, lane);

    const int KT = K >> 5;
    for (int kt = 0; kt < KT; ++kt) {
        __syncthreads();                       // vmcnt(0): buf[cur] ready; prev reads drained
        const int cur = kt & 1;
        if (kt + 1 < KT) {                     // prefetch next K-slab into other buffer
            stage_tile(A + (kt + 1) * 32, lda, &As[cur ^ 1][0], w, lane);
            stage_tile(B + (kt + 1) * 32, ldb, &Bs[cur ^ 1][0], w, lane);
        }
        const int kofs = (lane >> 4) << 3;     // k-group of 8 per 16-lane cohort
        bf16x8 av[4], bv[4];
#pragma unroll
        for (int i = 0; i < 4; ++i)
            av[i] = *(const bf16x8*)&As[cur][(wm * 64 + i * 16 + (lane & 15)) * 32 + kofs];
#pragma unroll
        for (int j = 0; j < 4; ++j)
            bv[j] = *(const bf16x8*)&Bs[cur][(wn * 64 + j * 16 + (lane & 15)) * 32 + kofs];
#pragma unroll
        for (int i = 0; i < 4; ++i)
#pragma unroll
            for (int j = 0; j < 4; ++j)
                acc[i][j] = __builtin_amdgcn_mfma_f32_16x16x32_bf16(av[i], bv[j], acc[i][j], 0, 0, 0);
    }

    const int r0 = blockIdx.y * 128 + wm * 64;
    const int c0 = blockIdx.x * 128 + wn * 64;
    const int lcol = lane & 15, lrow = (lane >> 4) << 2;
#pragma unroll
    for (int i = 0; i < 4; ++i)
#pragma unroll
        for (int j = 0; j < 4; ++j) {
            const int row = r0 + i * 16 + lrow;
            const int col = c0 + j * 16 + lcol;
#pragma unroll
            for (int r = 0; r < 4; ++r)
                storeC(&C[(long)(row + r) * ldc + col], acc[i][j][r]);
        }
}

// ---------- converts ----------
__global__ __launch_bounds__(256) void f2b8(const float* __restrict__ in, bf16* __restrict__ out, int n)
{
    int i = (blockIdx.x * 256 + threadIdx.x) * 8;
    if (i >= n) return;
    float4 a = *(const float4*)(in + i);
    float4 b = *(const float4*)(in + i + 4);
    union { bf16 h[8]; uint4 u; } pk;
    pk.h[0] = __float2bfloat16(a.x); pk.h[1] = __float2bfloat16(a.y);
    pk.h[2] = __float2bfloat16(a.z); pk.h[3] = __float2bfloat16(a.w);
    pk.h[4] = __float2bfloat16(b.x); pk.h[5] = __float2bfloat16(b.y);
    pk.h[6] = __float2bfloat16(b.z); pk.h[7] = __float2bfloat16(b.w);
    *(uint4*)(out + i) = pk.u;
}

// woUrB[j][h*128+c] = bf16(wo_u[j][c*8+h])   (128 x 1024)
__global__ __launch_bounds__(256) void reorder_wo_b(const float* __restrict__ wo, bf16* __restrict__ wor)
{
    int i = blockIdx.x * 256 + threadIdx.x;   // 131072
    int j = i >> 10, col = i & 1023;
    int h = col >> 7, c = col & 127;
    wor[i] = __float2bfloat16(wo[j * 1024 + c * 8 + h]);
}

__global__ __launch_bounds__(64) void zero8(float* p)
{
    if (threadIdx.x < 8) p[threadIdx.x] = 0.f;
}

// ---------- stats / softmax (same math as round 3; bf16 softmax outputs) ----------
__global__ __launch_bounds__(256) void stats_bh(const float* __restrict__ x, float* __restrict__ stats)
{
    const float* p = x + (long)blockIdx.x * 16384;
    float s1 = 0.f, s2 = 0.f;
    for (int i = threadIdx.x; i < 16384; i += 256) { float v = p[i]; s1 += v; s2 += v * v; }
    __shared__ float r1[256], r2[256];
    int t = threadIdx.x;
    r1[t] = s1; r2[t] = s2; __syncthreads();
    for (int o = 128; o > 0; o >>= 1) {
        if (t < o) { r1[t] += r1[t + o]; r2[t] += r2[t + o]; }
        __syncthreads();
    }
    if (t == 0) {
        float mu = r1[0] * (1.f / 16384.f);
        float var = r2[0] * (1.f / 16384.f) - mu * mu;
        stats[blockIdx.x * 2] = mu;
        stats[blockIdx.x * 2 + 1] = rsqrtf(var + 1e-5f);
    }
}

__global__ __launch_bounds__(256) void stats_big(const float* __restrict__ x, float* __restrict__ red)
{
    const float* p = x + (long)blockIdx.y * 4194304 + (long)blockIdx.x * 65536;
    float s1 = 0.f, s2 = 0.f;
    for (int i = threadIdx.x; i < 65536; i += 256) { float v = p[i]; s1 += v; s2 += v * v; }
    __shared__ float r1[256], r2[256];
    int t = threadIdx.x;
    r1[t] = s1; r2[t] = s2; __syncthreads();
    for (int o = 128; o > 0; o >>= 1) {
        if (t < o) { r1[t] += r1[t + o]; r2[t] += r2[t + o]; }
        __syncthreads();
    }
    if (t == 0) {
        atomicAdd(&red[blockIdx.y * 2], r1[0]);
        atomicAdd(&red[blockIdx.y * 2 + 1], r2[0]);
    }
}

// row=(b*8+h)*128+c: normalize by stats[bh], softmax over 128 -> bf16 out
__global__ __launch_bounds__(128) void softmax_row128(const float* __restrict__ attn,
                                                      const float* __restrict__ stats,
                                                      bf16* __restrict__ out)
{
    const int row = blockIdx.x;
    const int bh = row >> 7;
    const float mu = stats[bh * 2], rs = stats[bh * 2 + 1];
    const float* p = attn + (long)row * 128;
    const int t = threadIdx.x;
    float x = (p[t] - mu) * rs;
    float m = x;
#pragma unroll
    for (int o = 32; o > 0; o >>= 1) m = fmaxf(m, __shfl_xor(m, o));
    __shared__ float sm[2], ss[2];
    if ((t & 63) == 0) sm[t >> 6] = m;
    __syncthreads();
    m = fmaxf(sm[0], sm[1]);
    float e = expf(x - m);
    float s = e;
#pragma unroll
    for (int o = 32; o > 0; o >>= 1) s += __shfl_xor(s, o);
    if ((t & 63) == 0) ss[t >> 6] = s;
    __syncthreads();
    s = ss[0] + ss[1];
    out[(long)row * 128 + t] = __float2bfloat16(e / s);
}

// row=b*1024+c: normalize by red[b], softmax over 4096 -> bf16 out
__global__ __launch_bounds__(256) void softmax_row4096(const float* __restrict__ attn2,
                                                       const float* __restrict__ red,
                                                       bf16* __restrict__ out)
{
    const int row = blockIdx.x;
    const int b = row >> 10;
    const float inv = 1.f / 4194304.f;
    float mu = red[b * 2] * inv;
    float var = red[b * 2 + 1] * inv - mu * mu;
    float rs = rsqrtf(var + 1e-5f);
    const float* p = attn2 + (long)row * 4096;
    bf16* q = out + (long)row * 4096;
    const int t = threadIdx.x;
    float v[16];
    float mx = -3.0e38f;
#pragma unroll
    for (int i = 0; i < 16; ++i) { float u = (p[i * 256 + t] - mu) * rs; v[i] = u; mx = fmaxf(mx, u); }
#pragma unroll
    for (int o = 32; o > 0; o >>= 1) mx = fmaxf(mx, __shfl_xor(mx, o));
    __shared__ float sm[4], ss[4];
    if ((t & 63) == 0) sm[t >> 6] = mx;
    __syncthreads();
    mx = fmaxf(fmaxf(sm[0], sm[1]), fmaxf(sm[2], sm[3]));
    float s = 0.f;
#pragma unroll
    for (int i = 0; i < 16; ++i) { v[i] = expf(v[i] - mx); s += v[i]; }
#pragma unroll
    for (int o = 32; o > 0; o >>= 1) s += __shfl_xor(s, o);
    if ((t & 63) == 0) ss[t >> 6] = s;
    __syncthreads();
    s = ss[0] + ss[1] + ss[2] + ss[3];
    float r = 1.f / s;
#pragma unroll
    for (int i = 0; i < 16; ++i) q[i * 256 + t] = __float2bfloat16(v[i] * r);
}

// ---------------------------------------------------------------------------
extern "C" void kernel_launch(void* const* d_in, const int* in_sizes, int n_in,
                              void* d_out, int out_size, void* d_ws, size_t ws_size,
                              hipStream_t stream)
{
    const float* emb   = (const float*)d_in[0];
    const float* wq_uu = (const float*)d_in[1];
    const float* wk_uu = (const float*)d_in[2];
    const float* wv_uu = (const float*)d_in[3];
    const float* wq_lu = (const float*)d_in[4];
    const float* wk_lu = (const float*)d_in[5];
    const float* wv_lu = (const float*)d_in[6];
    const float* wo_u  = (const float*)d_in[7];
    const float* wo_l  = (const float*)d_in[8];
    float* out = (float*)d_out;

    // ---- workspace plan (~146 MB), U = 16,777,216 bf16 elems = 33.5 MB ----
    const long U = 16777216;
    bf16*  ws     = (bf16*)d_ws;
    bf16*  slot0  = ws;                 // QuT -> QlT -> sim2
    bf16*  slot1  = ws + U;             // KuT -> K2T -> V2
    float* attn2F = (float*)(ws + 2 * U); // 16.8M floats; also hosts (in time order):
    float* attnU  = attn2F;               //   [0..0.5M f32) upper logits
    bf16*  VuB    = (bf16*)attn2F;        //   [0..U) bf16 Vu
    bf16*  ctxUB  = (bf16*)attn2F + U;    //   [U..2U) bf16 ctxU
    bf16*  ctx2B  = (bf16*)attn2F;        //   [0..U) bf16 ctx2 (after attn2 dead)
    bf16*  embB   = ws + 4 * U;           // 4,194,304
    bf16*  wB     = embB + 4194304;       // 8 x 131072
    bf16*  wqUU = wB,            *wkUU = wB + 131072, *wvUU = wB + 262144;
    bf16*  wqLU = wB + 393216,   *wkLU = wB + 524288, *wvLU = wB + 655360;
    bf16*  woUrB = wB + 786432,  *woLB = wB + 917504;
    bf16*  simU   = wB + 1048576;         // 524,288
    float* statsF = (float*)(simU + 524288);
    float* statsU = statsF;               // 64
    float* red2   = statsF + 64;          // 8

    bf16* embB_l = embB;                  // [4][4096][128]
    bf16* embB_u = embB + 2097152;

    dim3 blk(256);

    // ---- converts ----
    f2b8<<<dim3(2048), blk, 0, stream>>>(emb, embB, 4194304);
    f2b8<<<dim3(64), blk, 0, stream>>>(wq_uu, wqUU, 131072);
    f2b8<<<dim3(64), blk, 0, stream>>>(wk_uu, wkUU, 131072);
    f2b8<<<dim3(64), blk, 0, stream>>>(wv_uu, wvUU, 131072);
    f2b8<<<dim3(64), blk, 0, stream>>>(wq_lu, wqLU, 131072);
    f2b8<<<dim3(64), blk, 0, stream>>>(wk_lu, wkLU, 131072);
    f2b8<<<dim3(64), blk, 0, stream>>>(wv_lu, wvLU, 131072);
    f2b8<<<dim3(64), blk, 0, stream>>>(wo_l, woLB, 131072);
    reorder_wo_b<<<dim3(512), blk, 0, stream>>>(wo_u, woUrB);

    // ---- upper path ----
    // QuT[b][o=1024][n=4096] = sum_k wq_uu[o,k] * emb_u[b][n,k]
    gemm_mfma_nt<bf16><<<dim3(32, 8, 4), blk, 0, stream>>>(
        wqUU, embB_u, slot0, 128, 128, 128, 4096, 1, 0, 0, 524288, 0, 4194304, 0);
    gemm_mfma_nt<bf16><<<dim3(32, 8, 4), blk, 0, stream>>>(
        wkUU, embB_u, slot1, 128, 128, 128, 4096, 1, 0, 0, 524288, 0, 4194304, 0);

    // attnU[bh][c][d] = sum_n QuT[b][hc+c][n] * KuT[b][hc+d][n]  (128x128, K=4096)
    gemm_mfma_nt<float><<<dim3(1, 1, 32), blk, 0, stream>>>(
        slot0, slot1, attnU, 4096, 4096, 4096, 128,
        8, 4194304, 524288, 4194304, 524288, 131072, 16384);

    stats_bh<<<dim3(32), blk, 0, stream>>>(attnU, statsU);
    softmax_row128<<<dim3(4096), dim3(128), 0, stream>>>(attnU, statsU, simU);

    // Vu[b][n][o=1024] = sum_k emb_u[b][n,k] * wv_uu[o,k]
    gemm_mfma_nt<bf16><<<dim3(8, 32, 4), blk, 0, stream>>>(
        embB_u, wvUU, VuB, 128, 128, 128, 1024, 1, 524288, 0, 0, 0, 4194304, 0);

    // ctxU[b][n][h*128+c] = sum_d Vu[b][n][h*128+d] * simU[bh][c][d]
    gemm_mfma_nt<bf16><<<dim3(1, 32, 32), blk, 0, stream>>>(
        VuB, simU, ctxUB, 128, 1024, 128, 1024,
        8, 4194304, 128, 131072, 16384, 4194304, 128);

    // O_u[bn][j] = sum_hc ctxU[bn][hc] * woUr[j][hc] -> out rows [4..8)
    gemm_mfma_nt<float><<<dim3(1, 128, 1), blk, 0, stream>>>(
        ctxUB, woUrB, out + 2097152L, 1024, 1024, 1024, 128, 1, 0, 0, 0, 0, 0, 0);

    // ---- lower path ----
    // QlT[b][c=1024][n=4096]
    gemm_mfma_nt<bf16><<<dim3(32, 8, 4), blk, 0, stream>>>(
        wqLU, embB_l, slot0, 128, 128, 128, 4096, 1, 0, 0, 524288, 0, 4194304, 0);
    // K2T[bp*1024+o][n=4096]
    gemm_mfma_nt<bf16><<<dim3(32, 8, 4), blk, 0, stream>>>(
        wkLU, embB_u, slot1, 128, 128, 128, 4096, 1, 0, 0, 524288, 0, 4194304, 0);

    // attn2[b][c][d] = sum_n QlT[b][c][n] * K2T[d][n]   (1024x4096, K=4096)
    gemm_mfma_nt<float><<<dim3(32, 8, 4), blk, 0, stream>>>(
        slot0, slot1, attn2F, 4096, 4096, 4096, 4096,
        1, 4194304, 0, 0, 0, 4194304, 0);

    zero8<<<dim3(1), dim3(64), 0, stream>>>(red2);
    stats_big<<<dim3(64, 4), blk, 0, stream>>>(attn2F, red2);
    softmax_row4096<<<dim3(4096), blk, 0, stream>>>(attn2F, red2, slot0);  // sim2 -> slot0

    // V2[n][bp*1024+o] = sum_k emb_u[bp][n,k] * wv_lu[o,k]  (into slot1)
    gemm_mfma_nt<bf16><<<dim3(8, 32, 4), blk, 0, stream>>>(
        embB_u, wvLU, slot1, 128, 128, 128, 4096, 1, 524288, 0, 0, 0, 1024, 0);

    // ctx2[b][n][c] = sum_d V2[n][d] * sim2[b][c][d]   (4096x1024, K=4096)
    gemm_mfma_nt<bf16><<<dim3(8, 32, 4), blk, 0, stream>>>(
        slot1, slot0, ctx2B, 4096, 4096, 4096, 1024,
        1, 0, 0, 4194304, 0, 4194304, 0);

    // O_l[bn][j] = sum_hc ctx2[bn][hc] * wo_l[j][hc] -> out rows [0..4)
    gemm_mfma_nt<float><<<dim3(1, 128, 1), blk, 0, stream>>>(
        ctx2B, woLB, out, 1024, 1024, 1024, 128, 1, 0, 0, 0, 0, 0, 0);
}

// Round 5
// 651.125 us; speedup vs baseline: 6.6565x; 1.1539x over previous
//
#include <hip/hip_runtime.h>
#include <hip/hip_bf16.h>

using bf16 = __hip_bfloat16;
typedef __attribute__((ext_vector_type(8))) short bf16x8;
typedef __attribute__((ext_vector_type(4))) float f32x4;

// ---------- store helpers ----------
static __device__ __forceinline__ void storeC(float* p, float v) { *p = v; }
static __device__ __forceinline__ void storeC(bf16* p, float v) { *p = __float2bfloat16(v); }

// ---------- async global->LDS (16B per lane, wave-uniform LDS base) ----------
static __device__ __forceinline__ void gl2lds16(const bf16* g, bf16* l)
{
    __builtin_amdgcn_global_load_lds(
        (const __attribute__((address_space(1))) unsigned int*)g,
        (__attribute__((address_space(3))) unsigned int*)l, 16, 0, 0);
}

// stage a 128x32 bf16 tile (global row-major, ld elems) into LDS [128][32]
static __device__ __forceinline__ void stage_tile(const bf16* gtile, int ld, bf16* ltile, int w, int lane)
{
    const bf16* g0 = gtile + (long)(w * 32 + (lane >> 2)) * ld + ((lane & 3) << 3);
    gl2lds16(g0, ltile + (w * 32) * 32);
    gl2lds16(g0 + (long)16 * ld, ltile + (w * 32 + 16) * 32);
}

// ---------------------------------------------------------------------------
// 128x128 MFMA NT GEMM (round-4 proven) for small/medium GEMMs.
// ---------------------------------------------------------------------------
template <typename TC>
__global__ __launch_bounds__(256) void gemm_mfma_nt(
    const bf16* __restrict__ A0, const bf16* __restrict__ B0, TC* __restrict__ C0,
    int K, int lda, int ldb, int ldc, int zdiv,
    long sAhi, long sAlo, long sBhi, long sBlo, long sChi, long sClo)
{
    __shared__ bf16 As[2][4096];
    __shared__ bf16 Bs[2][4096];
    const int z = blockIdx.z;
    const bf16* A = A0 + (long)(z / zdiv) * sAhi + (long)(z % zdiv) * sAlo + (long)blockIdx.y * 128 * lda;
    const bf16* B = B0 + (long)(z / zdiv) * sBhi + (long)(z % zdiv) * sBlo + (long)blockIdx.x * 128 * ldb;
    TC*       C = C0 + (long)(z / zdiv) * sChi + (long)(z % zdiv) * sClo;

    const int t = threadIdx.x, lane = t & 63, w = t >> 6;
    const int wm = w >> 1, wn = w & 1;

    f32x4 acc[4][4] = {};

    stage_tile(A, lda, &As[0][0], w, lane);
    stage_tile(B, ldb, &Bs[0][0], w, lane);

    const int KT = K >> 5;
    for (int kt = 0; kt < KT; ++kt) {
        __syncthreads();
        const int cur = kt & 1;
        if (kt + 1 < KT) {
            stage_tile(A + (kt + 1) * 32, lda, &As[cur ^ 1][0], w, lane);
            stage_tile(B + (kt + 1) * 32, ldb, &Bs[cur ^ 1][0], w, lane);
        }
        const int kofs = (lane >> 4) << 3;
        bf16x8 av[4], bv[4];
#pragma unroll
        for (int i = 0; i < 4; ++i)
            av[i] = *(const bf16x8*)&As[cur][(wm * 64 + i * 16 + (lane & 15)) * 32 + kofs];
#pragma unroll
        for (int j = 0; j < 4; ++j)
            bv[j] = *(const bf16x8*)&Bs[cur][(wn * 64 + j * 16 + (lane & 15)) * 32 + kofs];
#pragma unroll
        for (int i = 0; i < 4; ++i)
#pragma unroll
            for (int j = 0; j < 4; ++j)
                acc[i][j] = __builtin_amdgcn_mfma_f32_16x16x32_bf16(av[i], bv[j], acc[i][j], 0, 0, 0);
    }

    const int r0 = blockIdx.y * 128 + wm * 64;
    const int c0 = blockIdx.x * 128 + wn * 64;
    const int lcol = lane & 15, lrow = (lane >> 4) << 2;
#pragma unroll
    for (int i = 0; i < 4; ++i)
#pragma unroll
        for (int j = 0; j < 4; ++j) {
            const int row = r0 + i * 16 + lrow;
            const int col = c0 + j * 16 + lcol;
#pragma unroll
            for (int r = 0; r < 4; ++r)
                storeC(&C[(long)(row + r) * ldc + col], acc[i][j][r]);
        }
}

// ---------------------------------------------------------------------------
// 256x256 8-phase MFMA NT GEMM (big-K workhorse).
// BK=64, 512 thr = 8 waves (2Mx4N), per-wave C = 128x64 (acc[8][4]).
// LDS 128 KiB dynamic: buf{0,1} x { A[256][64] | B[256][64] }, chunk-XOR swizzle:
//   logical (row, 8-elem chunk g) lives at chunk (g ^ (row&7))  [within-row]
// Staged linearly via global_load_lds with inverse-swizzled SOURCE address.
// Raw s_barrier phases; single vmcnt(0) per K-tile (loads stay in flight
// across all phase barriers). K multiple of 64; M,N multiples of 256.
// ---------------------------------------------------------------------------
static __device__ __forceinline__ void stage256(const bf16* gtile, int ld, bf16* ldsregion, int t)
{
    const int row_in = t >> 3;          // 0..63
    const int pc = t & 7;               // physical chunk
    const int w = t >> 6;
#pragma unroll
    for (int q = 0; q < 4; ++q) {
        const int row = q * 64 + row_in;
        const int col = ((pc ^ (row & 7)) << 3);   // inverse-swizzled source col
        gl2lds16(gtile + (long)row * ld + col, ldsregion + q * 4096 + w * 512);
    }
}

template <typename TC>
__global__ __launch_bounds__(512, 2) void gemm_mfma_nt256(
    const bf16* __restrict__ A0, const bf16* __restrict__ B0, TC* __restrict__ C0,
    int K, int lda, int ldb, int ldc, long sA, long sB, long sC)
{
    extern __shared__ bf16 lds[];       // 65536 bf16 = 128 KiB
    const int z = blockIdx.z;
    const bf16* A = A0 + (long)z * sA + (long)blockIdx.y * 256 * lda;
    const bf16* B = B0 + (long)z * sB + (long)blockIdx.x * 256 * ldb;
    TC*       C = C0 + (long)z * sC;

    const int t = threadIdx.x, lane = t & 63, w = t >> 6;
    const int wm = w >> 2, wn = w & 3;       // 2 x 4 wave grid
    const int lr = lane & 15, lg = lane >> 4;

    f32x4 acc[8][4] = {};

    // prologue: stage K-tile 0 into buf 0
    stage256(A, lda, lds, t);
    stage256(B, ldb, lds + 16384, t);
    asm volatile("s_waitcnt vmcnt(0)" ::: "memory");
    __builtin_amdgcn_s_barrier();

    const int KT = K >> 6;
    for (int kt = 0; kt < KT; ++kt) {
        const int cur = kt & 1;
        bf16* Abuf  = lds + cur * 32768;
        bf16* Bbuf  = Abuf + 16384;
        bf16* AbufN = lds + (cur ^ 1) * 32768;

        // issue all 8 stage loads for K-tile kt+1 (they ride across all phase barriers)
        if (kt + 1 < KT) {
            stage256(A + (kt + 1) * 64, lda, AbufN, t);
            stage256(B + (kt + 1) * 64, ldb, AbufN + 16384, t);
        }

        // B fragments for the whole K-tile (8 x ds_read_b128), held in regs
        bf16x8 bfrag[4][2];
#pragma unroll
        for (int j = 0; j < 4; ++j)
#pragma unroll
            for (int s = 0; s < 2; ++s) {
                const int r = wn * 64 + j * 16 + lr;
                const int g = s * 4 + lg;
                bfrag[j][s] = *(const bf16x8*)&Bbuf[r * 64 + ((g ^ (r & 7)) << 3)];
            }

        // 4 phases: 2 M-tiles each, 16 MFMA per phase
#pragma unroll
        for (int p = 0; p < 4; ++p) {
            bf16x8 afrag[2][2];
#pragma unroll
            for (int i = 0; i < 2; ++i)
#pragma unroll
                for (int s = 0; s < 2; ++s) {
                    const int r = wm * 128 + (p * 2 + i) * 16 + lr;
                    const int g = s * 4 + lg;
                    afrag[i][s] = *(const bf16x8*)&Abuf[r * 64 + ((g ^ (r & 7)) << 3)];
                }
            __builtin_amdgcn_s_barrier();
            __builtin_amdgcn_s_setprio(1);
#pragma unroll
            for (int i = 0; i < 2; ++i)
#pragma unroll
                for (int j = 0; j < 4; ++j) {
                    acc[p * 2 + i][j] = __builtin_amdgcn_mfma_f32_16x16x32_bf16(afrag[i][0], bfrag[j][0], acc[p * 2 + i][j], 0, 0, 0);
                    acc[p * 2 + i][j] = __builtin_amdgcn_mfma_f32_16x16x32_bf16(afrag[i][1], bfrag[j][1], acc[p * 2 + i][j], 0, 0, 0);
                }
            __builtin_amdgcn_s_setprio(0);
            __builtin_amdgcn_s_barrier();
        }

        // buf swap: only point where we wait on the prefetch
        asm volatile("s_waitcnt vmcnt(0)" ::: "memory");
        __builtin_amdgcn_s_barrier();
    }

    const int r0 = blockIdx.y * 256 + wm * 128 + (lg << 2);
    const int c0 = blockIdx.x * 256 + wn * 64 + lr;
#pragma unroll
    for (int i = 0; i < 8; ++i)
#pragma unroll
        for (int j = 0; j < 4; ++j) {
            const int row = r0 + i * 16;
            const int col = c0 + j * 16;
#pragma unroll
            for (int rr = 0; rr < 4; ++rr)
                storeC(&C[(long)(row + rr) * ldc + col], acc[i][j][rr]);
        }
}

// ---------- converts ----------
__global__ __launch_bounds__(256) void f2b8(const float* __restrict__ in, bf16* __restrict__ out, int n)
{
    int i = (blockIdx.x * 256 + threadIdx.x) * 8;
    if (i >= n) return;
    float4 a = *(const float4*)(in + i);
    float4 b = *(const float4*)(in + i + 4);
    union { bf16 h[8]; uint4 u; } pk;
    pk.h[0] = __float2bfloat16(a.x); pk.h[1] = __float2bfloat16(a.y);
    pk.h[2] = __float2bfloat16(a.z); pk.h[3] = __float2bfloat16(a.w);
    pk.h[4] = __float2bfloat16(b.x); pk.h[5] = __float2bfloat16(b.y);
    pk.h[6] = __float2bfloat16(b.z); pk.h[7] = __float2bfloat16(b.w);
    *(uint4*)(out + i) = pk.u;
}

// woUrB[j][h*128+c] = bf16(wo_u[j][c*8+h])   (128 x 1024)
__global__ __launch_bounds__(256) void reorder_wo_b(const float* __restrict__ wo, bf16* __restrict__ wor)
{
    int i = blockIdx.x * 256 + threadIdx.x;   // 131072
    int j = i >> 10, col = i & 1023;
    int h = col >> 7, c = col & 127;
    wor[i] = __float2bfloat16(wo[j * 1024 + c * 8 + h]);
}

__global__ __launch_bounds__(64) void zero8(float* p)
{
    if (threadIdx.x < 8) p[threadIdx.x] = 0.f;
}

// ---------- stats / softmax ----------
__global__ __launch_bounds__(256) void stats_bh(const float* __restrict__ x, float* __restrict__ stats)
{
    const float* p = x + (long)blockIdx.x * 16384;
    float s1 = 0.f, s2 = 0.f;
    for (int i = threadIdx.x; i < 16384; i += 256) { float v = p[i]; s1 += v; s2 += v * v; }
    __shared__ float r1[256], r2[256];
    int t = threadIdx.x;
    r1[t] = s1; r2[t] = s2; __syncthreads();
    for (int o = 128; o > 0; o >>= 1) {
        if (t < o) { r1[t] += r1[t + o]; r2[t] += r2[t + o]; }
        __syncthreads();
    }
    if (t == 0) {
        float mu = r1[0] * (1.f / 16384.f);
        float var = r2[0] * (1.f / 16384.f) - mu * mu;
        stats[blockIdx.x * 2] = mu;
        stats[blockIdx.x * 2 + 1] = rsqrtf(var + 1e-5f);
    }
}

__global__ __launch_bounds__(256) void stats_big(const float* __restrict__ x, float* __restrict__ red)
{
    const float* p = x + (long)blockIdx.y * 4194304 + (long)blockIdx.x * 65536;
    float s1 = 0.f, s2 = 0.f;
    for (int i = threadIdx.x; i < 65536; i += 256) { float v = p[i]; s1 += v; s2 += v * v; }
    __shared__ float r1[256], r2[256];
    int t = threadIdx.x;
    r1[t] = s1; r2[t] = s2; __syncthreads();
    for (int o = 128; o > 0; o >>= 1) {
        if (t < o) { r1[t] += r1[t + o]; r2[t] += r2[t + o]; }
        __syncthreads();
    }
    if (t == 0) {
        atomicAdd(&red[blockIdx.y * 2], r1[0]);
        atomicAdd(&red[blockIdx.y * 2 + 1], r2[0]);
    }
}

__global__ __launch_bounds__(128) void softmax_row128(const float* __restrict__ attn,
                                                      const float* __restrict__ stats,
                                                      bf16* __restrict__ out)
{
    const int row = blockIdx.x;
    const int bh = row >> 7;
    const float mu = stats[bh * 2], rs = stats[bh * 2 + 1];
    const float* p = attn + (long)row * 128;
    const int t = threadIdx.x;
    float x = (p[t] - mu) * rs;
    float m = x;
#pragma unroll
    for (int o = 32; o > 0; o >>= 1) m = fmaxf(m, __shfl_xor(m, o));
    __shared__ float sm[2], ss[2];
    if ((t & 63) == 0) sm[t >> 6] = m;
    __syncthreads();
    m = fmaxf(sm[0], sm[1]);
    float e = expf(x - m);
    float s = e;
#pragma unroll
    for (int o = 32; o > 0; o >>= 1) s += __shfl_xor(s, o);
    if ((t & 63) == 0) ss[t >> 6] = s;
    __syncthreads();
    s = ss[0] + ss[1];
    out[(long)row * 128 + t] = __float2bfloat16(e / s);
}

__global__ __launch_bounds__(256) void softmax_row4096(const float* __restrict__ attn2,
                                                       const float* __restrict__ red,
                                                       bf16* __restrict__ out)
{
    const int row = blockIdx.x;
    const int b = row >> 10;
    const float inv = 1.f / 4194304.f;
    float mu = red[b * 2] * inv;
    float var = red[b * 2 + 1] * inv - mu * mu;
    float rs = rsqrtf(var + 1e-5f);
    const float* p = attn2 + (long)row * 4096;
    bf16* q = out + (long)row * 4096;
    const int t = threadIdx.x;
    float v[16];
    float mx = -3.0e38f;
#pragma unroll
    for (int i = 0; i < 16; ++i) { float u = (p[i * 256 + t] - mu) * rs; v[i] = u; mx = fmaxf(mx, u); }
#pragma unroll
    for (int o = 32; o > 0; o >>= 1) mx = fmaxf(mx, __shfl_xor(mx, o));
    __shared__ float sm[4], ss[4];
    if ((t & 63) == 0) sm[t >> 6] = mx;
    __syncthreads();
    mx = fmaxf(fmaxf(sm[0], sm[1]), fmaxf(sm[2], sm[3]));
    float s = 0.f;
#pragma unroll
    for (int i = 0; i < 16; ++i) { v[i] = expf(v[i] - mx); s += v[i]; }
#pragma unroll
    for (int o = 32; o > 0; o >>= 1) s += __shfl_xor(s, o);
    if ((t & 63) == 0) ss[t >> 6] = s;
    __syncthreads();
    s = ss[0] + ss[1] + ss[2] + ss[3];
    float r = 1.f / s;
#pragma unroll
    for (int i = 0; i < 16; ++i) q[i * 256 + t] = __float2bfloat16(v[i] * r);
}

// ---------------------------------------------------------------------------
extern "C" void kernel_launch(void* const* d_in, const int* in_sizes, int n_in,
                              void* d_out, int out_size, void* d_ws, size_t ws_size,
                              hipStream_t stream)
{
    const float* emb   = (const float*)d_in[0];
    const float* wq_uu = (const float*)d_in[1];
    const float* wk_uu = (const float*)d_in[2];
    const float* wv_uu = (const float*)d_in[3];
    const float* wq_lu = (const float*)d_in[4];
    const float* wk_lu = (const float*)d_in[5];
    const float* wv_lu = (const float*)d_in[6];
    const float* wo_u  = (const float*)d_in[7];
    const float* wo_l  = (const float*)d_in[8];
    float* out = (float*)d_out;

    // enable 128 KiB dynamic LDS for the 256^2 kernels (idempotent)
    hipFuncSetAttribute(reinterpret_cast<const void*>(&gemm_mfma_nt256<float>),
                        hipFuncAttributeMaxDynamicSharedMemorySize, 131072);
    hipFuncSetAttribute(reinterpret_cast<const void*>(&gemm_mfma_nt256<bf16>),
                        hipFuncAttributeMaxDynamicSharedMemorySize, 131072);

    // ---- workspace plan (~146 MB), U = 16,777,216 bf16 elems = 33.5 MB ----
    const long U = 16777216;
    bf16*  ws     = (bf16*)d_ws;
    bf16*  slot0  = ws;                 // QuT -> QlT -> sim2
    bf16*  slot1  = ws + U;             // KuT -> K2T -> V2
    float* attn2F = (float*)(ws + 2 * U);
    float* attnU  = attn2F;
    bf16*  VuB    = (bf16*)attn2F;
    bf16*  ctxUB  = (bf16*)attn2F + U;
    bf16*  ctx2B  = (bf16*)attn2F;
    bf16*  embB   = ws + 4 * U;
    bf16*  wB     = embB + 4194304;
    bf16*  wqUU = wB,            *wkUU = wB + 131072, *wvUU = wB + 262144;
    bf16*  wqLU = wB + 393216,   *wkLU = wB + 524288, *wvLU = wB + 655360;
    bf16*  woUrB = wB + 786432,  *woLB = wB + 917504;
    bf16*  simU   = wB + 1048576;
    float* statsF = (float*)(simU + 524288);
    float* statsU = statsF;
    float* red2   = statsF + 64;

    bf16* embB_l = embB;
    bf16* embB_u = embB + 2097152;

    dim3 blk(256);

    // ---- converts ----
    f2b8<<<dim3(2048), blk, 0, stream>>>(emb, embB, 4194304);
    f2b8<<<dim3(64), blk, 0, stream>>>(wq_uu, wqUU, 131072);
    f2b8<<<dim3(64), blk, 0, stream>>>(wk_uu, wkUU, 131072);
    f2b8<<<dim3(64), blk, 0, stream>>>(wv_uu, wvUU, 131072);
    f2b8<<<dim3(64), blk, 0, stream>>>(wq_lu, wqLU, 131072);
    f2b8<<<dim3(64), blk, 0, stream>>>(wk_lu, wkLU, 131072);
    f2b8<<<dim3(64), blk, 0, stream>>>(wv_lu, wvLU, 131072);
    f2b8<<<dim3(64), blk, 0, stream>>>(wo_l, woLB, 131072);
    reorder_wo_b<<<dim3(512), blk, 0, stream>>>(wo_u, woUrB);

    // ---- upper path ----
    gemm_mfma_nt<bf16><<<dim3(32, 8, 4), blk, 0, stream>>>(
        wqUU, embB_u, slot0, 128, 128, 128, 4096, 1, 0, 0, 524288, 0, 4194304, 0);
    gemm_mfma_nt<bf16><<<dim3(32, 8, 4), blk, 0, stream>>>(
        wkUU, embB_u, slot1, 128, 128, 128, 4096, 1, 0, 0, 524288, 0, 4194304, 0);

    gemm_mfma_nt<float><<<dim3(1, 1, 32), blk, 0, stream>>>(
        slot0, slot1, attnU, 4096, 4096, 4096, 128,
        8, 4194304, 524288, 4194304, 524288, 131072, 16384);

    stats_bh<<<dim3(32), blk, 0, stream>>>(attnU, statsU);
    softmax_row128<<<dim3(4096), dim3(128), 0, stream>>>(attnU, statsU, simU);

    gemm_mfma_nt<bf16><<<dim3(8, 32, 4), blk, 0, stream>>>(
        embB_u, wvUU, VuB, 128, 128, 128, 1024, 1, 524288, 0, 0, 0, 4194304, 0);

    gemm_mfma_nt<bf16><<<dim3(1, 32, 32), blk, 0, stream>>>(
        VuB, simU, ctxUB, 128, 1024, 128, 1024,
        8, 4194304, 128, 131072, 16384, 4194304, 128);

    gemm_mfma_nt<float><<<dim3(1, 128, 1), blk, 0, stream>>>(
        ctxUB, woUrB, out + 2097152L, 1024, 1024, 1024, 128, 1, 0, 0, 0, 0, 0, 0);

    // ---- lower path ----
    gemm_mfma_nt<bf16><<<dim3(32, 8, 4), blk, 0, stream>>>(
        wqLU, embB_l, slot0, 128, 128, 128, 4096, 1, 0, 0, 524288, 0, 4194304, 0);
    gemm_mfma_nt<bf16><<<dim3(32, 8, 4), blk, 0, stream>>>(
        wkLU, embB_u, slot1, 128, 128, 128, 4096, 1, 0, 0, 524288, 0, 4194304, 0);

    // attn2[b][c][d] = sum_n QlT[b][c][n] * K2T[d][n]   (1024x4096, K=4096) — 256^2 8-phase
    gemm_mfma_nt256<float><<<dim3(16, 4, 4), dim3(512), 131072, stream>>>(
        slot0, slot1, attn2F, 4096, 4096, 4096, 4096,
        4194304, 0, 4194304);

    zero8<<<dim3(1), dim3(64), 0, stream>>>(red2);
    stats_big<<<dim3(64, 4), blk, 0, stream>>>(attn2F, red2);
    softmax_row4096<<<dim3(4096), blk, 0, stream>>>(attn2F, red2, slot0);  // sim2 -> slot0

    gemm_mfma_nt<bf16><<<dim3(8, 32, 4), blk, 0, stream>>>(
        embB_u, wvLU, slot1, 128, 128, 128, 4096, 1, 524288, 0, 0, 0, 1024, 0);

    // ctx2[b][n][c] = sum_d V2[n][d] * sim2[b][c][d]   (4096x1024, K=4096) — 256^2 8-phase
    gemm_mfma_nt256<bf16><<<dim3(4, 16, 4), dim3(512), 131072, stream>>>(
        slot1, slot0, ctx2B, 4096, 4096, 4096, 1024,
        0, 4194304, 4194304);

    gemm_mfma_nt<float><<<dim3(1, 128, 1), blk, 0, stream>>>(
        ctx2B, woLB, out, 1024, 1024, 1024, 128, 1, 0, 0, 0, 0, 0, 0);
}

// Round 6
// 504.646 us; speedup vs baseline: 8.5887x; 1.2903x over previous
//
#include <hip/hip_runtime.h>
#include <hip/hip_bf16.h>

using bf16 = __hip_bfloat16;
typedef __attribute__((ext_vector_type(8))) short bf16x8;
typedef __attribute__((ext_vector_type(4))) float f32x4;

// ---------- store helpers ----------
static __device__ __forceinline__ void storeC(float* p, float v) { *p = v; }
static __device__ __forceinline__ void storeC(bf16* p, float v) { *p = __float2bfloat16(v); }

// ---------- async global->LDS (16B per lane, wave-uniform LDS base) ----------
static __device__ __forceinline__ void gl2lds16(const bf16* g, bf16* l)
{
    __builtin_amdgcn_global_load_lds(
        (const __attribute__((address_space(1))) unsigned int*)g,
        (__attribute__((address_space(3))) unsigned int*)l, 16, 0, 0);
}

// stage a 128x32 bf16 tile (global row-major, ld elems) into LDS [128][32]
static __device__ __forceinline__ void stage_tile(const bf16* gtile, int ld, bf16* ltile, int w, int lane)
{
    const bf16* g0 = gtile + (long)(w * 32 + (lane >> 2)) * ld + ((lane & 3) << 3);
    gl2lds16(g0, ltile + (w * 32) * 32);
    gl2lds16(g0 + (long)16 * ld, ltile + (w * 32 + 16) * 32);
}

// ---------------------------------------------------------------------------
// 128x128 MFMA NT GEMM (proven) for small/medium GEMMs. Optional atomic-add C.
// ---------------------------------------------------------------------------
template <typename TC, bool ATOMIC>
__global__ __launch_bounds__(256) void gemm_mfma_nt(
    const bf16* __restrict__ A0, const bf16* __restrict__ B0, TC* __restrict__ C0,
    int K, int lda, int ldb, int ldc, int zdiv,
    long sAhi, long sAlo, long sBhi, long sBlo, long sChi, long sClo)
{
    __shared__ bf16 As[2][4096];
    __shared__ bf16 Bs[2][4096];
    const int z = blockIdx.z;
    const bf16* A = A0 + (long)(z / zdiv) * sAhi + (long)(z % zdiv) * sAlo + (long)blockIdx.y * 128 * lda;
    const bf16* B = B0 + (long)(z / zdiv) * sBhi + (long)(z % zdiv) * sBlo + (long)blockIdx.x * 128 * ldb;
    TC*       C = C0 + (long)(z / zdiv) * sChi + (long)(z % zdiv) * sClo;

    const int t = threadIdx.x, lane = t & 63, w = t >> 6;
    const int wm = w >> 1, wn = w & 1;

    f32x4 acc[4][4] = {};

    stage_tile(A, lda, &As[0][0], w, lane);
    stage_tile(B, ldb, &Bs[0][0], w, lane);

    const int KT = K >> 5;
    for (int kt = 0; kt < KT; ++kt) {
        __syncthreads();
        const int cur = kt & 1;
        if (kt + 1 < KT) {
            stage_tile(A + (kt + 1) * 32, lda, &As[cur ^ 1][0], w, lane);
            stage_tile(B + (kt + 1) * 32, ldb, &Bs[cur ^ 1][0], w, lane);
        }
        const int kofs = (lane >> 4) << 3;
        bf16x8 av[4], bv[4];
#pragma unroll
        for (int i = 0; i < 4; ++i)
            av[i] = *(const bf16x8*)&As[cur][(wm * 64 + i * 16 + (lane & 15)) * 32 + kofs];
#pragma unroll
        for (int j = 0; j < 4; ++j)
            bv[j] = *(const bf16x8*)&Bs[cur][(wn * 64 + j * 16 + (lane & 15)) * 32 + kofs];
#pragma unroll
        for (int i = 0; i < 4; ++i)
#pragma unroll
            for (int j = 0; j < 4; ++j)
                acc[i][j] = __builtin_amdgcn_mfma_f32_16x16x32_bf16(av[i], bv[j], acc[i][j], 0, 0, 0);
    }

    const int r0 = blockIdx.y * 128 + wm * 64;
    const int c0 = blockIdx.x * 128 + wn * 64;
    const int lcol = lane & 15, lrow = (lane >> 4) << 2;
#pragma unroll
    for (int i = 0; i < 4; ++i)
#pragma unroll
        for (int j = 0; j < 4; ++j) {
            const int row = r0 + i * 16 + lrow;
            const int col = c0 + j * 16 + lcol;
#pragma unroll
            for (int r = 0; r < 4; ++r) {
                if constexpr (ATOMIC)
                    atomicAdd(&C[(long)(row + r) * ldc + col], acc[i][j][r]);
                else
                    storeC(&C[(long)(row + r) * ldc + col], acc[i][j][r]);
            }
        }
}

// ---------------------------------------------------------------------------
// 256x256 MFMA NT GEMM, chunked depth-3 pipeline (counted vmcnt, T4).
// BK=32 chunks, 4 LDS buffers (128 KiB), 512 thr = 8 waves (2Mx4N),
// per-wave C = 128x64 (acc[8][4]). Swizzle: phys chunk = g ^ ((row>>1)&3)
// (row&1 already varies the bank half; XOR with the bits above it -> 2-way).
// Staged linearly (dest = t*16B) with inverse-swizzled global source col.
// One s_barrier per chunk; stage for c+3 issued AFTER the barrier (all waves
// have drained buf[(c-1)&3] reads via MFMA's implicit lgkm waits).
// STATS: fused per-block sum/sumsq atomicAdd into red[z*2..] (instance-norm).
// ---------------------------------------------------------------------------
template <typename TC, bool STATS>
__global__ __launch_bounds__(512, 2) void gemm_mfma_nt256(
    const bf16* __restrict__ A0, const bf16* __restrict__ B0, TC* __restrict__ C0,
    int K, int lda, int ldb, int ldc, long sA, long sB, long sC, float* __restrict__ red)
{
    extern __shared__ bf16 lds[];       // 4 bufs x (A 8192 + B 8192) elems = 128 KiB
    const int z = blockIdx.z;
    const bf16* A = A0 + (long)z * sA + (long)blockIdx.y * 256 * lda;
    const bf16* B = B0 + (long)z * sB + (long)blockIdx.x * 256 * ldb;
    TC*       C = C0 + (long)z * sC;

    const int t = threadIdx.x, lane = t & 63, w = t >> 6;
    const int wm = w >> 2, wn = w & 3;       // 2 x 4 wave grid
    const int lr = lane & 15, lg = lane >> 4;

    f32x4 acc[8][4] = {};
    const int KT = K >> 5;

    const int srow = t >> 2, spc = t & 3;    // stage: row-in-sweep, phys chunk
    auto STAGE = [&](int c) {
        bf16* base = lds + (c & 3) * 16384;
        const bf16* Ag = A + c * 32;
        const bf16* Bg = B + c * 32;
        int r0 = srow, r1 = srow + 128;
        int c0 = (spc ^ ((r0 >> 1) & 3)) << 3;
        int c1 = (spc ^ ((r1 >> 1) & 3)) << 3;
        gl2lds16(Ag + (long)r0 * lda + c0, base + w * 512);
        gl2lds16(Ag + (long)r1 * lda + c1, base + 4096 + w * 512);
        gl2lds16(Bg + (long)r0 * ldb + c0, base + 8192 + w * 512);
        gl2lds16(Bg + (long)r1 * ldb + c1, base + 12288 + w * 512);
    };

    if (KT > 0) STAGE(0);
    if (KT > 1) STAGE(1);
    if (KT > 2) STAGE(2);

    for (int c = 0; c < KT; ++c) {
        const int rem = KT - 1 - c;
        if (rem >= 2)      asm volatile("s_waitcnt vmcnt(8)" ::: "memory");
        else if (rem == 1) asm volatile("s_waitcnt vmcnt(4)" ::: "memory");
        else               asm volatile("s_waitcnt vmcnt(0)" ::: "memory");
        __builtin_amdgcn_s_barrier();
        asm volatile("" ::: "memory");       // keep ds_reads below the barrier
        if (c + 3 < KT) STAGE(c + 3);

        const bf16* Ab = lds + (c & 3) * 16384;
        const bf16* Bb = Ab + 8192;
        bf16x8 bfrag[4], afrag[8];
#pragma unroll
        for (int j = 0; j < 4; ++j) {
            const int r = wn * 64 + j * 16 + lr;
            bfrag[j] = *(const bf16x8*)&Bb[r * 32 + ((lg ^ ((r >> 1) & 3)) << 3)];
        }
#pragma unroll
        for (int i = 0; i < 8; ++i) {
            const int r = wm * 128 + i * 16 + lr;
            afrag[i] = *(const bf16x8*)&Ab[r * 32 + ((lg ^ ((r >> 1) & 3)) << 3)];
        }
        __builtin_amdgcn_s_setprio(1);
#pragma unroll
        for (int i = 0; i < 8; ++i)
#pragma unroll
            for (int j = 0; j < 4; ++j)
                acc[i][j] = __builtin_amdgcn_mfma_f32_16x16x32_bf16(afrag[i], bfrag[j], acc[i][j], 0, 0, 0);
        __builtin_amdgcn_s_setprio(0);
    }

    const int r0 = blockIdx.y * 256 + wm * 128 + (lg << 2);
    const int c0 = blockIdx.x * 256 + wn * 64 + lr;
#pragma unroll
    for (int i = 0; i < 8; ++i)
#pragma unroll
        for (int j = 0; j < 4; ++j) {
#pragma unroll
            for (int rr = 0; rr < 4; ++rr)
                storeC(&C[(long)(r0 + i * 16 + rr) * ldc + (c0 + j * 16)], acc[i][j][rr]);
        }

    if constexpr (STATS) {
        float s1 = 0.f, s2 = 0.f;
#pragma unroll
        for (int i = 0; i < 8; ++i)
#pragma unroll
            for (int j = 0; j < 4; ++j)
#pragma unroll
                for (int rr = 0; rr < 4; ++rr) {
                    float v = acc[i][j][rr];
                    s1 += v; s2 += v * v;
                }
#pragma unroll
        for (int o = 32; o > 0; o >>= 1) { s1 += __shfl_xor(s1, o); s2 += __shfl_xor(s2, o); }
        __syncthreads();                      // LDS free now
        float* rb = (float*)lds;
        if (lane == 0) { rb[w] = s1; rb[8 + w] = s2; }
        __syncthreads();
        if (t == 0) {
            float a = 0.f, b = 0.f;
#pragma unroll
            for (int i = 0; i < 8; ++i) { a += rb[i]; b += rb[8 + i]; }
            atomicAdd(&red[z * 2], a);
            atomicAdd(&red[z * 2 + 1], b);
        }
    }
}

// ---------- converts ----------
__global__ __launch_bounds__(256) void f2b8(const float* __restrict__ in, bf16* __restrict__ out, int n)
{
    int i = (blockIdx.x * 256 + threadIdx.x) * 8;
    if (i >= n) return;
    float4 a = *(const float4*)(in + i);
    float4 b = *(const float4*)(in + i + 4);
    union { bf16 h[8]; uint4 u; } pk;
    pk.h[0] = __float2bfloat16(a.x); pk.h[1] = __float2bfloat16(a.y);
    pk.h[2] = __float2bfloat16(a.z); pk.h[3] = __float2bfloat16(a.w);
    pk.h[4] = __float2bfloat16(b.x); pk.h[5] = __float2bfloat16(b.y);
    pk.h[6] = __float2bfloat16(b.z); pk.h[7] = __float2bfloat16(b.w);
    *(uint4*)(out + i) = pk.u;
}

// 7 weight matrices (131072 floats each) -> contiguous bf16 block
__global__ __launch_bounds__(256) void convert_w7(
    const float* p0, const float* p1, const float* p2, const float* p3,
    const float* p4, const float* p5, const float* p6, bf16* __restrict__ dst)
{
    const float* srcs[7] = {p0, p1, p2, p3, p4, p5, p6};
    const float* in = srcs[blockIdx.y];
    bf16* out = dst + (long)blockIdx.y * 131072;
    int i = (blockIdx.x * 256 + threadIdx.x) * 8;   // gridDim.x = 64
    float4 a = *(const float4*)(in + i);
    float4 b = *(const float4*)(in + i + 4);
    union { bf16 h[8]; uint4 u; } pk;
    pk.h[0] = __float2bfloat16(a.x); pk.h[1] = __float2bfloat16(a.y);
    pk.h[2] = __float2bfloat16(a.z); pk.h[3] = __float2bfloat16(a.w);
    pk.h[4] = __float2bfloat16(b.x); pk.h[5] = __float2bfloat16(b.y);
    pk.h[6] = __float2bfloat16(b.z); pk.h[7] = __float2bfloat16(b.w);
    *(uint4*)(out + i) = pk.u;
}

// woUrB[j][h*128+c] = bf16(wo_u[j][c*8+h])   (128 x 1024)
__global__ __launch_bounds__(256) void reorder_wo_b(const float* __restrict__ wo, bf16* __restrict__ wor)
{
    int i = blockIdx.x * 256 + threadIdx.x;   // 131072
    int j = i >> 10, col = i & 1023;
    int h = col >> 7, c = col & 127;
    wor[i] = __float2bfloat16(wo[j * 1024 + c * 8 + h]);
}

__global__ __launch_bounds__(64) void zero8(float* p)
{
    if (threadIdx.x < 8) p[threadIdx.x] = 0.f;
}

__global__ __launch_bounds__(256) void zero_f4(float* __restrict__ p)   // grid*256*4 floats
{
    int i = (blockIdx.x * 256 + threadIdx.x) * 4;
    *(float4*)(p + i) = float4{0.f, 0.f, 0.f, 0.f};
}

// ---------- stats / softmax ----------
__global__ __launch_bounds__(256) void stats_bh(const float* __restrict__ x, float* __restrict__ stats)
{
    const float* p = x + (long)blockIdx.x * 16384;
    float s1 = 0.f, s2 = 0.f;
    for (int i = threadIdx.x; i < 16384; i += 256) { float v = p[i]; s1 += v; s2 += v * v; }
    __shared__ float r1[256], r2[256];
    int t = threadIdx.x;
    r1[t] = s1; r2[t] = s2; __syncthreads();
    for (int o = 128; o > 0; o >>= 1) {
        if (t < o) { r1[t] += r1[t + o]; r2[t] += r2[t + o]; }
        __syncthreads();
    }
    if (t == 0) {
        float mu = r1[0] * (1.f / 16384.f);
        float var = r2[0] * (1.f / 16384.f) - mu * mu;
        stats[blockIdx.x * 2] = mu;
        stats[blockIdx.x * 2 + 1] = rsqrtf(var + 1e-5f);
    }
}

__global__ __launch_bounds__(128) void softmax_row128(const float* __restrict__ attn,
                                                      const float* __restrict__ stats,
                                                      bf16* __restrict__ out)
{
    const int row = blockIdx.x;
    const int bh = row >> 7;
    const float mu = stats[bh * 2], rs = stats[bh * 2 + 1];
    const float* p = attn + (long)row * 128;
    const int t = threadIdx.x;
    float x = (p[t] - mu) * rs;
    float m = x;
#pragma unroll
    for (int o = 32; o > 0; o >>= 1) m = fmaxf(m, __shfl_xor(m, o));
    __shared__ float sm[2], ss[2];
    if ((t & 63) == 0) sm[t >> 6] = m;
    __syncthreads();
    m = fmaxf(sm[0], sm[1]);
    float e = expf(x - m);
    float s = e;
#pragma unroll
    for (int o = 32; o > 0; o >>= 1) s += __shfl_xor(s, o);
    if ((t & 63) == 0) ss[t >> 6] = s;
    __syncthreads();
    s = ss[0] + ss[1];
    out[(long)row * 128 + t] = __float2bfloat16(e / s);
}

__global__ __launch_bounds__(256) void softmax_row4096(const float* __restrict__ attn2,
                                                       const float* __restrict__ red,
                                                       bf16* __restrict__ out)
{
    const int row = blockIdx.x;
    const int b = row >> 10;
    const float inv = 1.f / 4194304.f;
    float mu = red[b * 2] * inv;
    float var = red[b * 2 + 1] * inv - mu * mu;
    float rs = rsqrtf(var + 1e-5f);
    const float* p = attn2 + (long)row * 4096;
    bf16* q = out + (long)row * 4096;
    const int t = threadIdx.x;
    float v[16];
    float mx = -3.0e38f;
#pragma unroll
    for (int i = 0; i < 16; ++i) { float u = (p[i * 256 + t] - mu) * rs; v[i] = u; mx = fmaxf(mx, u); }
#pragma unroll
    for (int o = 32; o > 0; o >>= 1) mx = fmaxf(mx, __shfl_xor(mx, o));
    __shared__ float sm[4], ss[4];
    if ((t & 63) == 0) sm[t >> 6] = mx;
    __syncthreads();
    mx = fmaxf(fmaxf(sm[0], sm[1]), fmaxf(sm[2], sm[3]));
    float s = 0.f;
#pragma unroll
    for (int i = 0; i < 16; ++i) { v[i] = expf(v[i] - mx); s += v[i]; }
#pragma unroll
    for (int o = 32; o > 0; o >>= 1) s += __shfl_xor(s, o);
    if ((t & 63) == 0) ss[t >> 6] = s;
    __syncthreads();
    s = ss[0] + ss[1] + ss[2] + ss[3];
    float r = 1.f / s;
#pragma unroll
    for (int i = 0; i < 16; ++i) q[i * 256 + t] = __float2bfloat16(v[i] * r);
}

// ---------------------------------------------------------------------------
extern "C" void kernel_launch(void* const* d_in, const int* in_sizes, int n_in,
                              void* d_out, int out_size, void* d_ws, size_t ws_size,
                              hipStream_t stream)
{
    const float* emb   = (const float*)d_in[0];
    const float* wq_uu = (const float*)d_in[1];
    const float* wk_uu = (const float*)d_in[2];
    const float* wv_uu = (const float*)d_in[3];
    const float* wq_lu = (const float*)d_in[4];
    const float* wk_lu = (const float*)d_in[5];
    const float* wv_lu = (const float*)d_in[6];
    const float* wo_u  = (const float*)d_in[7];
    const float* wo_l  = (const float*)d_in[8];
    float* out = (float*)d_out;

    hipFuncSetAttribute(reinterpret_cast<const void*>(&gemm_mfma_nt256<float, true>),
                        hipFuncAttributeMaxDynamicSharedMemorySize, 131072);
    hipFuncSetAttribute(reinterpret_cast<const void*>(&gemm_mfma_nt256<bf16, false>),
                        hipFuncAttributeMaxDynamicSharedMemorySize, 131072);

    // ---- workspace plan (~172 MB), U = 16,777,216 elems (32 MiB bf16) ----
    const long U = 16777216;
    bf16*  ws     = (bf16*)d_ws;
    bf16*  slot0  = ws;                   // QuT -> QlT -> sim2
    bf16*  slot1  = ws + U;               // KuT -> K2T -> V2
    float* attn2F = (float*)(ws + 2 * U); // 16.7M floats [64,128) MiB; also in time order:
    float* attnU  = attn2F;               //   0.5M f32 upper logits
    bf16*  VuB    = (bf16*)attn2F;        //   [64,96) MiB bf16 Vu
    bf16*  ctx2B  = (bf16*)attn2F;        //   [64,96) MiB bf16 ctx2 (after attn2 dead)
    bf16*  embB   = ws + 4 * U;           // 4,194,304
    bf16*  wB     = embB + 4194304;       // 8 x 131072: wqUU wkUU wvUU wqLU wkLU wvLU woL woUr
    bf16*  wqUU  = wB;
    bf16*  wvUU  = wB + 262144;
    bf16*  wqLU  = wB + 393216;
    bf16*  wvLU  = wB + 655360;
    bf16*  woLB  = wB + 786432;
    bf16*  woUrB = wB + 917504;
    bf16*  simU   = wB + 1048576;         // 524,288
    float* statsF = (float*)(simU + 524288);
    float* statsU = statsF;               // 64
    float* red2   = statsF + 64;          // 8
    bf16*  ctxUB  = (bf16*)(statsF + 128);// U elems, survives attn2

    bf16* embB_l = embB;                  // [4][4096][128]
    bf16* embB_u = embB + 2097152;

    dim3 blk(256);

    // ---- converts & zero-init ----
    f2b8<<<dim3(2048), blk, 0, stream>>>(emb, embB, 4194304);
    convert_w7<<<dim3(64, 7), blk, 0, stream>>>(wq_uu, wk_uu, wv_uu, wq_lu, wk_lu, wv_lu, wo_l, wB);
    reorder_wo_b<<<dim3(512), blk, 0, stream>>>(wo_u, woUrB);
    zero8<<<dim3(1), dim3(64), 0, stream>>>(red2);

    // ---- upper path ----
    // QuT+KuT merged: z=(q*4+b): A=w(q), B=emb_u[b], C=slot(q)[b]  (2048 blocks)
    gemm_mfma_nt<bf16, false><<<dim3(32, 8, 8), blk, 0, stream>>>(
        wqUU, embB_u, slot0, 128, 128, 128, 4096,
        4, 131072, 0, 0, 524288, 16777216, 4194304);

    zero_f4<<<dim3(512), blk, 0, stream>>>(attnU);

    // attnU K-split x8: z=(bh*8+kc), atomicAdd C  (256 blocks)
    gemm_mfma_nt<float, true><<<dim3(1, 1, 256), blk, 0, stream>>>(
        slot0, slot1, attnU, 512, 4096, 4096, 128,
        8, 524288, 512, 524288, 512, 16384, 0);

    stats_bh<<<dim3(32), blk, 0, stream>>>(attnU, statsU);
    softmax_row128<<<dim3(4096), dim3(128), 0, stream>>>(attnU, statsU, simU);

    // Vu
    gemm_mfma_nt<bf16, false><<<dim3(8, 32, 4), blk, 0, stream>>>(
        embB_u, wvUU, VuB, 128, 128, 128, 1024, 1, 524288, 0, 0, 0, 4194304, 0);

    // ctxU -> dedicated region (survives attn2)
    gemm_mfma_nt<bf16, false><<<dim3(1, 32, 32), blk, 0, stream>>>(
        VuB, simU, ctxUB, 128, 1024, 128, 1024,
        8, 4194304, 128, 131072, 16384, 4194304, 128);

    // ---- lower path ----
    // QlT+K2T merged: z=(q*4+b): A=w(q), B=emb(l/u)[b], C=slot(q)[b]
    gemm_mfma_nt<bf16, false><<<dim3(32, 8, 8), blk, 0, stream>>>(
        wqLU, embB_l, slot0, 128, 128, 128, 4096,
        4, 131072, 0, 2097152, 524288, 16777216, 4194304);

    // attn2 (256^2 chunked pipeline) + fused per-b stats
    gemm_mfma_nt256<float, true><<<dim3(16, 4, 4), dim3(512), 131072, stream>>>(
        slot0, slot1, attn2F, 4096, 4096, 4096, 4096,
        4194304, 0, 4194304, red2);

    softmax_row4096<<<dim3(4096), blk, 0, stream>>>(attn2F, red2, slot0);  // sim2 -> slot0

    // V2
    gemm_mfma_nt<bf16, false><<<dim3(8, 32, 4), blk, 0, stream>>>(
        embB_u, wvLU, slot1, 128, 128, 128, 4096, 1, 524288, 0, 0, 0, 1024, 0);

    // ctx2 (256^2 chunked pipeline)
    gemm_mfma_nt256<bf16, false><<<dim3(4, 16, 4), dim3(512), 131072, stream>>>(
        slot1, slot0, ctx2B, 4096, 4096, 4096, 1024,
        0, 4194304, 4194304, nullptr);

    // O_l + O_u merged: z=0 -> (ctx2B, woLB) -> out[0..4); z=1 -> (ctxUB, woUrB) -> out[4..8)
    gemm_mfma_nt<float, false><<<dim3(1, 128, 2), blk, 0, stream>>>(
        ctx2B, woLB, out, 1024, 1024, 1024, 128,
        1, (long)(ctxUB - ctx2B), 0, 131072, 0, 2097152, 0);
}

// Round 7
// 500.462 us; speedup vs baseline: 8.6605x; 1.0084x over previous
//
#include <hip/hip_runtime.h>
#include <hip/hip_bf16.h>

using bf16 = __hip_bfloat16;
typedef __attribute__((ext_vector_type(8))) short bf16x8;
typedef __attribute__((ext_vector_type(4))) float f32x4;

// ---------- store helpers ----------
static __device__ __forceinline__ void storeC(float* p, float v) { *p = v; }
static __device__ __forceinline__ void storeC(bf16* p, float v) { *p = __float2bfloat16(v); }

// ---------- async global->LDS (16B per lane, wave-uniform LDS base) ----------
static __device__ __forceinline__ void gl2lds16(const bf16* g, bf16* l)
{
    __builtin_amdgcn_global_load_lds(
        (const __attribute__((address_space(1))) unsigned int*)g,
        (__attribute__((address_space(3))) unsigned int*)l, 16, 0, 0);
}

// stage a 128x32 bf16 tile (global row-major, ld elems) into LDS [128][32]
static __device__ __forceinline__ void stage_tile(const bf16* gtile, int ld, bf16* ltile, int w, int lane)
{
    const bf16* g0 = gtile + (long)(w * 32 + (lane >> 2)) * ld + ((lane & 3) << 3);
    gl2lds16(g0, ltile + (w * 32) * 32);
    gl2lds16(g0 + (long)16 * ld, ltile + (w * 32 + 16) * 32);
}

// ---------------------------------------------------------------------------
// 128x128 MFMA NT GEMM (proven) for small/medium GEMMs. Optional atomic-add C.
// ---------------------------------------------------------------------------
template <typename TC, bool ATOMIC>
__global__ __launch_bounds__(256) void gemm_mfma_nt(
    const bf16* __restrict__ A0, const bf16* __restrict__ B0, TC* __restrict__ C0,
    int K, int lda, int ldb, int ldc, int zdiv,
    long sAhi, long sAlo, long sBhi, long sBlo, long sChi, long sClo)
{
    __shared__ bf16 As[2][4096];
    __shared__ bf16 Bs[2][4096];
    const int z = blockIdx.z;
    const bf16* A = A0 + (long)(z / zdiv) * sAhi + (long)(z % zdiv) * sAlo + (long)blockIdx.y * 128 * lda;
    const bf16* B = B0 + (long)(z / zdiv) * sBhi + (long)(z % zdiv) * sBlo + (long)blockIdx.x * 128 * ldb;
    TC*       C = C0 + (long)(z / zdiv) * sChi + (long)(z % zdiv) * sClo;

    const int t = threadIdx.x, lane = t & 63, w = t >> 6;
    const int wm = w >> 1, wn = w & 1;

    f32x4 acc[4][4] = {};

    stage_tile(A, lda, &As[0][0], w, lane);
    stage_tile(B, ldb, &Bs[0][0], w, lane);

    const int KT = K >> 5;
    for (int kt = 0; kt < KT; ++kt) {
        __syncthreads();
        const int cur = kt & 1;
        if (kt + 1 < KT) {
            stage_tile(A + (kt + 1) * 32, lda, &As[cur ^ 1][0], w, lane);
            stage_tile(B + (kt + 1) * 32, ldb, &Bs[cur ^ 1][0], w, lane);
        }
        const int kofs = (lane >> 4) << 3;
        bf16x8 av[4], bv[4];
#pragma unroll
        for (int i = 0; i < 4; ++i)
            av[i] = *(const bf16x8*)&As[cur][(wm * 64 + i * 16 + (lane & 15)) * 32 + kofs];
#pragma unroll
        for (int j = 0; j < 4; ++j)
            bv[j] = *(const bf16x8*)&Bs[cur][(wn * 64 + j * 16 + (lane & 15)) * 32 + kofs];
#pragma unroll
        for (int i = 0; i < 4; ++i)
#pragma unroll
            for (int j = 0; j < 4; ++j)
                acc[i][j] = __builtin_amdgcn_mfma_f32_16x16x32_bf16(av[i], bv[j], acc[i][j], 0, 0, 0);
    }

    const int r0 = blockIdx.y * 128 + wm * 64;
    const int c0 = blockIdx.x * 128 + wn * 64;
    const int lcol = lane & 15, lrow = (lane >> 4) << 2;
#pragma unroll
    for (int i = 0; i < 4; ++i)
#pragma unroll
        for (int j = 0; j < 4; ++j) {
            const int row = r0 + i * 16 + lrow;
            const int col = c0 + j * 16 + lcol;
#pragma unroll
            for (int r = 0; r < 4; ++r) {
                if constexpr (ATOMIC)
                    atomicAdd(&C[(long)(row + r) * ldc + col], acc[i][j][r]);
                else
                    storeC(&C[(long)(row + r) * ldc + col], acc[i][j][r]);
            }
        }
}

// ---------------------------------------------------------------------------
// 256x256 MFMA NT GEMM, chunked depth-3 pipeline + 2-phase interleave.
// BK=32 chunks, 4 LDS buffers (128 KiB), 512 thr = 8 waves (2Mx4N),
// per-wave C = 128x64 (acc[8][4]). Swizzle: phys chunk = g ^ ((row>>1)&3).
// Per chunk: top counted-vmcnt barrier, then
//   phase A: { read bfrag[4]+afrag[0..3], stage A-half of c+3, bar,
//              setprio(1), 16 MFMA (rows 0-3), setprio(0), bar }
//   phase B: { read afrag[4..7],          stage B-half of c+3, bar,
//              setprio(1), 16 MFMA (rows 4-7), setprio(0), bar }
// Race-safety: a wave's chunk-(c-1) ds_reads are consumed by its MFMAs before
// it reaches the chunk-c top barrier, so buf[(c+3)&3]==buf[(c-1)&3] may be
// overwritten after it. vmcnt never drains to 0 until the tail (T4).
// STATS: fused per-block sum/sumsq atomicAdd into red[z*2..] (instance-norm).
// ---------------------------------------------------------------------------
template <typename TC, bool STATS>
__global__ __launch_bounds__(512, 2) void gemm_mfma_nt256(
    const bf16* __restrict__ A0, const bf16* __restrict__ B0, TC* __restrict__ C0,
    int K, int lda, int ldb, int ldc, long sA, long sB, long sC, float* __restrict__ red)
{
    extern __shared__ bf16 lds[];       // 4 bufs x (A 8192 + B 8192) elems = 128 KiB
    const int z = blockIdx.z;
    const bf16* A = A0 + (long)z * sA + (long)blockIdx.y * 256 * lda;
    const bf16* B = B0 + (long)z * sB + (long)blockIdx.x * 256 * ldb;
    TC*       C = C0 + (long)z * sC;

    const int t = threadIdx.x, lane = t & 63, w = t >> 6;
    const int wm = w >> 2, wn = w & 3;       // 2 x 4 wave grid
    const int lr = lane & 15, lg = lane >> 4;

    f32x4 acc[8][4] = {};
    const int KT = K >> 5;

    const int srow = t >> 2, spc = t & 3;    // stage: row-in-sweep, phys chunk
    auto STAGE_A = [&](int c) {
        bf16* base = lds + (c & 3) * 16384;
        const bf16* Ag = A + c * 32;
        const int r0 = srow, r1 = srow + 128;
        gl2lds16(Ag + (long)r0 * lda + ((spc ^ ((r0 >> 1) & 3)) << 3), base + w * 512);
        gl2lds16(Ag + (long)r1 * lda + ((spc ^ ((r1 >> 1) & 3)) << 3), base + 4096 + w * 512);
    };
    auto STAGE_B = [&](int c) {
        bf16* base = lds + (c & 3) * 16384 + 8192;
        const bf16* Bg = B + c * 32;
        const int r0 = srow, r1 = srow + 128;
        gl2lds16(Bg + (long)r0 * ldb + ((spc ^ ((r0 >> 1) & 3)) << 3), base + w * 512);
        gl2lds16(Bg + (long)r1 * ldb + ((spc ^ ((r1 >> 1) & 3)) << 3), base + 4096 + w * 512);
    };

    if (KT > 0) { STAGE_A(0); STAGE_B(0); }
    if (KT > 1) { STAGE_A(1); STAGE_B(1); }
    if (KT > 2) { STAGE_A(2); STAGE_B(2); }

    for (int c = 0; c < KT; ++c) {
        const int rem = KT - 1 - c;
        if (rem >= 2)      asm volatile("s_waitcnt vmcnt(8)" ::: "memory");
        else if (rem == 1) asm volatile("s_waitcnt vmcnt(4)" ::: "memory");
        else               asm volatile("s_waitcnt vmcnt(0)" ::: "memory");
        __builtin_amdgcn_s_barrier();
        asm volatile("" ::: "memory");       // keep this chunk's ds_reads below

        const bf16* Ab = lds + (c & 3) * 16384;
        const bf16* Bb = Ab + 8192;
        const bool pf = (c + 3 < KT);

        // ---- phase A ----
        bf16x8 bfrag[4], afragA[4];
#pragma unroll
        for (int j = 0; j < 4; ++j) {
            const int r = wn * 64 + j * 16 + lr;
            bfrag[j] = *(const bf16x8*)&Bb[r * 32 + ((lg ^ ((r >> 1) & 3)) << 3)];
        }
#pragma unroll
        for (int i = 0; i < 4; ++i) {
            const int r = wm * 128 + i * 16 + lr;
            afragA[i] = *(const bf16x8*)&Ab[r * 32 + ((lg ^ ((r >> 1) & 3)) << 3)];
        }
        if (pf) STAGE_A(c + 3);
        __builtin_amdgcn_s_barrier();
        __builtin_amdgcn_s_setprio(1);
#pragma unroll
        for (int i = 0; i < 4; ++i)
#pragma unroll
            for (int j = 0; j < 4; ++j)
                acc[i][j] = __builtin_amdgcn_mfma_f32_16x16x32_bf16(afragA[i], bfrag[j], acc[i][j], 0, 0, 0);
        __builtin_amdgcn_s_setprio(0);
        __builtin_amdgcn_s_barrier();

        // ---- phase B ----
        bf16x8 afragB[4];
#pragma unroll
        for (int i = 0; i < 4; ++i) {
            const int r = wm * 128 + (4 + i) * 16 + lr;
            afragB[i] = *(const bf16x8*)&Ab[r * 32 + ((lg ^ ((r >> 1) & 3)) << 3)];
        }
        if (pf) STAGE_B(c + 3);
        __builtin_amdgcn_s_barrier();
        __builtin_amdgcn_s_setprio(1);
#pragma unroll
        for (int i = 0; i < 4; ++i)
#pragma unroll
            for (int j = 0; j < 4; ++j)
                acc[4 + i][j] = __builtin_amdgcn_mfma_f32_16x16x32_bf16(afragB[i], bfrag[j], acc[4 + i][j], 0, 0, 0);
        __builtin_amdgcn_s_setprio(0);
        __builtin_amdgcn_s_barrier();
    }

    const int r0 = blockIdx.y * 256 + wm * 128 + (lg << 2);
    const int c0 = blockIdx.x * 256 + wn * 64 + lr;
#pragma unroll
    for (int i = 0; i < 8; ++i)
#pragma unroll
        for (int j = 0; j < 4; ++j) {
#pragma unroll
            for (int rr = 0; rr < 4; ++rr)
                storeC(&C[(long)(r0 + i * 16 + rr) * ldc + (c0 + j * 16)], acc[i][j][rr]);
        }

    if constexpr (STATS) {
        float s1 = 0.f, s2 = 0.f;
#pragma unroll
        for (int i = 0; i < 8; ++i)
#pragma unroll
            for (int j = 0; j < 4; ++j)
#pragma unroll
                for (int rr = 0; rr < 4; ++rr) {
                    float v = acc[i][j][rr];
                    s1 += v; s2 += v * v;
                }
#pragma unroll
        for (int o = 32; o > 0; o >>= 1) { s1 += __shfl_xor(s1, o); s2 += __shfl_xor(s2, o); }
        __syncthreads();                      // LDS free now
        float* rb = (float*)lds;
        if (lane == 0) { rb[w] = s1; rb[8 + w] = s2; }
        __syncthreads();
        if (t == 0) {
            float a = 0.f, b = 0.f;
#pragma unroll
            for (int i = 0; i < 8; ++i) { a += rb[i]; b += rb[8 + i]; }
            atomicAdd(&red[z * 2], a);
            atomicAdd(&red[z * 2 + 1], b);
        }
    }
}

// ---------------------------------------------------------------------------
// prep: all setup work in one launch (3521 blocks x 256 thr)
//   [0,2048)    : emb f32 -> bf16 (4,194,304 elems)
//   [2048,2496) : 7 weight mats f32 -> bf16 into wB (order below)
//   [2496,3008) : wo_u reorder [j][c*8+h] -> bf16 [j][h*128+c]
//   [3008,3520) : zero attnU (524,288 f32)
//   [3520]      : zero red2 (8 f32)
// ---------------------------------------------------------------------------
__global__ __launch_bounds__(256) void prep(
    const float* __restrict__ emb,
    const float* w0, const float* w1, const float* w2, const float* w3,
    const float* w4, const float* w5, const float* w6,
    const float* __restrict__ wo_u,
    bf16* __restrict__ embB, bf16* __restrict__ wB, bf16* __restrict__ woUrB,
    float* __restrict__ attnU, float* __restrict__ red2)
{
    const int b = blockIdx.x;
    if (b < 2048 || (b >= 2048 && b < 2496)) {
        const float* in;
        bf16* out;
        int i;
        if (b < 2048) {
            in = emb; out = embB;
            i = (b * 256 + threadIdx.x) * 8;
        } else {
            const int sub = b - 2048;
            const float* srcs[7] = {w0, w1, w2, w3, w4, w5, w6};
            in = srcs[sub >> 6];
            out = wB + (long)(sub >> 6) * 131072;
            i = ((sub & 63) * 256 + threadIdx.x) * 8;
        }
        float4 a = *(const float4*)(in + i);
        float4 c = *(const float4*)(in + i + 4);
        union { bf16 h[8]; uint4 u; } pk;
        pk.h[0] = __float2bfloat16(a.x); pk.h[1] = __float2bfloat16(a.y);
        pk.h[2] = __float2bfloat16(a.z); pk.h[3] = __float2bfloat16(a.w);
        pk.h[4] = __float2bfloat16(c.x); pk.h[5] = __float2bfloat16(c.y);
        pk.h[6] = __float2bfloat16(c.z); pk.h[7] = __float2bfloat16(c.w);
        *(uint4*)(out + i) = pk.u;
    } else if (b < 3008) {
        int i = (b - 2496) * 256 + threadIdx.x;   // 131072
        int j = i >> 10, col = i & 1023;
        int h = col >> 7, cc = col & 127;
        woUrB[i] = __float2bfloat16(wo_u[j * 1024 + cc * 8 + h]);
    } else if (b < 3520) {
        int i = ((b - 3008) * 256 + threadIdx.x) * 4;
        *(float4*)(attnU + i) = float4{0.f, 0.f, 0.f, 0.f};
    } else {
        if (threadIdx.x < 8) red2[threadIdx.x] = 0.f;
    }
}

// ---------- stats / softmax ----------
__global__ __launch_bounds__(256) void stats_bh(const float* __restrict__ x, float* __restrict__ stats)
{
    const float* p = x + (long)blockIdx.x * 16384;
    float s1 = 0.f, s2 = 0.f;
    for (int i = threadIdx.x; i < 16384; i += 256) { float v = p[i]; s1 += v; s2 += v * v; }
    __shared__ float r1[256], r2[256];
    int t = threadIdx.x;
    r1[t] = s1; r2[t] = s2; __syncthreads();
    for (int o = 128; o > 0; o >>= 1) {
        if (t < o) { r1[t] += r1[t + o]; r2[t] += r2[t + o]; }
        __syncthreads();
    }
    if (t == 0) {
        float mu = r1[0] * (1.f / 16384.f);
        float var = r2[0] * (1.f / 16384.f) - mu * mu;
        stats[blockIdx.x * 2] = mu;
        stats[blockIdx.x * 2 + 1] = rsqrtf(var + 1e-5f);
    }
}

__global__ __launch_bounds__(128) void softmax_row128(const float* __restrict__ attn,
                                                      const float* __restrict__ stats,
                                                      bf16* __restrict__ out)
{
    const int row = blockIdx.x;
    const int bh = row >> 7;
    const float mu = stats[bh * 2], rs = stats[bh * 2 + 1];
    const float* p = attn + (long)row * 128;
    const int t = threadIdx.x;
    float x = (p[t] - mu) * rs;
    float m = x;
#pragma unroll
    for (int o = 32; o > 0; o >>= 1) m = fmaxf(m, __shfl_xor(m, o));
    __shared__ float sm[2], ss[2];
    if ((t & 63) == 0) sm[t >> 6] = m;
    __syncthreads();
    m = fmaxf(sm[0], sm[1]);
    float e = expf(x - m);
    float s = e;
#pragma unroll
    for (int o = 32; o > 0; o >>= 1) s += __shfl_xor(s, o);
    if ((t & 63) == 0) ss[t >> 6] = s;
    __syncthreads();
    s = ss[0] + ss[1];
    out[(long)row * 128 + t] = __float2bfloat16(e / s);
}

__global__ __launch_bounds__(256) void softmax_row4096(const float* __restrict__ attn2,
                                                       const float* __restrict__ red,
                                                       bf16* __restrict__ out)
{
    const int row = blockIdx.x;
    const int b = row >> 10;
    const float inv = 1.f / 4194304.f;
    float mu = red[b * 2] * inv;
    float var = red[b * 2 + 1] * inv - mu * mu;
    float rs = rsqrtf(var + 1e-5f);
    const float* p = attn2 + (long)row * 4096;
    bf16* q = out + (long)row * 4096;
    const int t = threadIdx.x;
    float v[16];
    float mx = -3.0e38f;
#pragma unroll
    for (int i = 0; i < 16; ++i) { float u = (p[i * 256 + t] - mu) * rs; v[i] = u; mx = fmaxf(mx, u); }
#pragma unroll
    for (int o = 32; o > 0; o >>= 1) mx = fmaxf(mx, __shfl_xor(mx, o));
    __shared__ float sm[4], ss[4];
    if ((t & 63) == 0) sm[t >> 6] = mx;
    __syncthreads();
    mx = fmaxf(fmaxf(sm[0], sm[1]), fmaxf(sm[2], sm[3]));
    float s = 0.f;
#pragma unroll
    for (int i = 0; i < 16; ++i) { v[i] = expf(v[i] - mx); s += v[i]; }
#pragma unroll
    for (int o = 32; o > 0; o >>= 1) s += __shfl_xor(s, o);
    if ((t & 63) == 0) ss[t >> 6] = s;
    __syncthreads();
    s = ss[0] + ss[1] + ss[2] + ss[3];
    float r = 1.f / s;
#pragma unroll
    for (int i = 0; i < 16; ++i) q[i * 256 + t] = __float2bfloat16(v[i] * r);
}

// ---------------------------------------------------------------------------
extern "C" void kernel_launch(void* const* d_in, const int* in_sizes, int n_in,
                              void* d_out, int out_size, void* d_ws, size_t ws_size,
                              hipStream_t stream)
{
    const float* emb   = (const float*)d_in[0];
    const float* wq_uu = (const float*)d_in[1];
    const float* wk_uu = (const float*)d_in[2];
    const float* wv_uu = (const float*)d_in[3];
    const float* wq_lu = (const float*)d_in[4];
    const float* wk_lu = (const float*)d_in[5];
    const float* wv_lu = (const float*)d_in[6];
    const float* wo_u  = (const float*)d_in[7];
    const float* wo_l  = (const float*)d_in[8];
    float* out = (float*)d_out;

    hipFuncSetAttribute(reinterpret_cast<const void*>(&gemm_mfma_nt256<float, true>),
                        hipFuncAttributeMaxDynamicSharedMemorySize, 131072);
    hipFuncSetAttribute(reinterpret_cast<const void*>(&gemm_mfma_nt256<bf16, false>),
                        hipFuncAttributeMaxDynamicSharedMemorySize, 131072);

    // ---- workspace plan (~180 MB), U = 16,777,216 elems (32 MiB bf16) ----
    const long U = 16777216;
    bf16*  ws     = (bf16*)d_ws;
    bf16*  slot0  = ws;                   // QuT -> QlT -> sim2
    bf16*  slot1  = ws + U;               // KuT -> K2T -> V2
    float* attn2F = (float*)(ws + 2 * U); // 16.7M floats; earlier: attnU / VuB / ctx2B
    float* attnU  = attn2F;
    bf16*  VuB    = (bf16*)attn2F;
    bf16*  ctx2B  = (bf16*)attn2F;
    bf16*  embB   = ws + 4 * U;           // 4,194,304
    bf16*  wB     = embB + 4194304;       // 7 x 131072: wqUU wkUU wqLU wkLU wvUU wvLU woL
    bf16*  wqUU  = wB;
    bf16*  wqLU  = wB + 262144;
    bf16*  wvUU  = wB + 524288;
    bf16*  wvLU  = wB + 655360;
    bf16*  woLB  = wB + 786432;
    bf16*  woUrB = wB + 917504;
    bf16*  simU   = wB + 1048576;         // 524,288
    float* statsF = (float*)(simU + 524288);
    float* statsU = statsF;               // 64
    float* red2   = statsF + 64;          // 8
    bf16*  ctxUB  = (bf16*)(statsF + 128);// U elems, survives attn2

    bf16* embB_l = embB;                  // [4][4096][128]
    bf16* embB_u = embB + 2097152;

    dim3 blk(256);

    // ---- all setup in one launch ----
    prep<<<dim3(3521), blk, 0, stream>>>(
        emb, wq_uu, wk_uu, wq_lu, wk_lu, wv_uu, wv_lu, wo_l, wo_u,
        embB, wB, woUrB, attnU, red2);

    // ---- upper path ----
    // QuT+KuT merged: z=(q*4+b): A=w(q), B=emb_u[b], C=slot(q)[b]  (2048 blocks)
    gemm_mfma_nt<bf16, false><<<dim3(32, 8, 8), blk, 0, stream>>>(
        wqUU, embB_u, slot0, 128, 128, 128, 4096,
        4, 131072, 0, 0, 524288, 16777216, 4194304);

    // attnU K-split x8: z=(bh*8+kc), atomicAdd C  (256 blocks)
    gemm_mfma_nt<float, true><<<dim3(1, 1, 256), blk, 0, stream>>>(
        slot0, slot1, attnU, 512, 4096, 4096, 128,
        8, 524288, 512, 524288, 512, 16384, 0);

    stats_bh<<<dim3(32), blk, 0, stream>>>(attnU, statsU);
    softmax_row128<<<dim3(4096), dim3(128), 0, stream>>>(attnU, statsU, simU);

    // Vu
    gemm_mfma_nt<bf16, false><<<dim3(8, 32, 4), blk, 0, stream>>>(
        embB_u, wvUU, VuB, 128, 128, 128, 1024, 1, 524288, 0, 0, 0, 4194304, 0);

    // ctxU -> dedicated region (survives attn2)
    gemm_mfma_nt<bf16, false><<<dim3(1, 32, 32), blk, 0, stream>>>(
        VuB, simU, ctxUB, 128, 1024, 128, 1024,
        8, 4194304, 128, 131072, 16384, 4194304, 128);

    // ---- lower path ----
    // QlT+K2T merged: z=(q*4+b): A=w(q+2), B=emb(l/u)[b], C=slot(q)[b]
    gemm_mfma_nt<bf16, false><<<dim3(32, 8, 8), blk, 0, stream>>>(
        wqLU, embB_l, slot0, 128, 128, 128, 4096,
        4, 131072, 0, 2097152, 524288, 16777216, 4194304);

    // attn2 (256^2 2-phase pipeline) + fused per-b stats
    gemm_mfma_nt256<float, true><<<dim3(16, 4, 4), dim3(512), 131072, stream>>>(
        slot0, slot1, attn2F, 4096, 4096, 4096, 4096,
        4194304, 0, 4194304, red2);

    softmax_row4096<<<dim3(4096), blk, 0, stream>>>(attn2F, red2, slot0);  // sim2 -> slot0

    // V2
    gemm_mfma_nt<bf16, false><<<dim3(8, 32, 4), blk, 0, stream>>>(
        embB_u, wvLU, slot1, 128, 128, 128, 4096, 1, 524288, 0, 0, 0, 1024, 0);

    // ctx2 (256^2 2-phase pipeline)
    gemm_mfma_nt256<bf16, false><<<dim3(4, 16, 4), dim3(512), 131072, stream>>>(
        slot1, slot0, ctx2B, 4096, 4096, 4096, 1024,
        0, 4194304, 4194304, nullptr);

    // O_l + O_u merged: z=0 -> (ctx2B, woLB) -> out[0..4); z=1 -> (ctxUB, woUrB) -> out[4..8)
    gemm_mfma_nt<float, false><<<dim3(1, 128, 2), blk, 0, stream>>>(
        ctx2B, woLB, out, 1024, 1024, 1024, 128,
        1, (long)(ctxUB - ctx2B), 0, 131072, 0, 2097152, 0);
}

// Round 8
// 451.120 us; speedup vs baseline: 9.6077x; 1.1094x over previous
//
#include <hip/hip_runtime.h>
#include <hip/hip_bf16.h>

using bf16 = __hip_bfloat16;
typedef __attribute__((ext_vector_type(8))) short bf16x8;
typedef __attribute__((ext_vector_type(4))) float f32x4;

// ---------- store helpers ----------
static __device__ __forceinline__ void storeC(float* p, float v) { *p = v; }
static __device__ __forceinline__ void storeC(bf16* p, float v) { *p = __float2bfloat16(v); }

// ---------- async global->LDS (16B per lane, wave-uniform LDS base) ----------
static __device__ __forceinline__ void gl2lds16(const bf16* g, bf16* l)
{
    __builtin_amdgcn_global_load_lds(
        (const __attribute__((address_space(1))) unsigned int*)g,
        (__attribute__((address_space(3))) unsigned int*)l, 16, 0, 0);
}

// stage a 128x32 bf16 tile (global row-major, ld elems) into LDS [128][32]
static __device__ __forceinline__ void stage_tile(const bf16* gtile, int ld, bf16* ltile, int w, int lane)
{
    const bf16* g0 = gtile + (long)(w * 32 + (lane >> 2)) * ld + ((lane & 3) << 3);
    gl2lds16(g0, ltile + (w * 32) * 32);
    gl2lds16(g0 + (long)16 * ld, ltile + (w * 32 + 16) * 32);
}

// ---------------------------------------------------------------------------
// 128x128 MFMA NT GEMM (proven). Optional atomic-add C.
// C[m,n] (+)= sum_k A[m*lda+k] * B[n*ldb+k]; z -> (z/zdiv, z%zdiv) strides.
// ---------------------------------------------------------------------------
template <typename TC, bool ATOMIC>
__global__ __launch_bounds__(256) void gemm_mfma_nt(
    const bf16* __restrict__ A0, const bf16* __restrict__ B0, TC* __restrict__ C0,
    int K, int lda, int ldb, int ldc, int zdiv,
    long sAhi, long sAlo, long sBhi, long sBlo, long sChi, long sClo)
{
    __shared__ bf16 As[2][4096];
    __shared__ bf16 Bs[2][4096];
    const int z = blockIdx.z;
    const bf16* A = A0 + (long)(z / zdiv) * sAhi + (long)(z % zdiv) * sAlo + (long)blockIdx.y * 128 * lda;
    const bf16* B = B0 + (long)(z / zdiv) * sBhi + (long)(z % zdiv) * sBlo + (long)blockIdx.x * 128 * ldb;
    TC*       C = C0 + (long)(z / zdiv) * sChi + (long)(z % zdiv) * sClo;

    const int t = threadIdx.x, lane = t & 63, w = t >> 6;
    const int wm = w >> 1, wn = w & 1;

    f32x4 acc[4][4] = {};

    stage_tile(A, lda, &As[0][0], w, lane);
    stage_tile(B, ldb, &Bs[0][0], w, lane);

    const int KT = K >> 5;
    for (int kt = 0; kt < KT; ++kt) {
        __syncthreads();
        const int cur = kt & 1;
        if (kt + 1 < KT) {
            stage_tile(A + (kt + 1) * 32, lda, &As[cur ^ 1][0], w, lane);
            stage_tile(B + (kt + 1) * 32, ldb, &Bs[cur ^ 1][0], w, lane);
        }
        const int kofs = (lane >> 4) << 3;
        bf16x8 av[4], bv[4];
#pragma unroll
        for (int i = 0; i < 4; ++i)
            av[i] = *(const bf16x8*)&As[cur][(wm * 64 + i * 16 + (lane & 15)) * 32 + kofs];
#pragma unroll
        for (int j = 0; j < 4; ++j)
            bv[j] = *(const bf16x8*)&Bs[cur][(wn * 64 + j * 16 + (lane & 15)) * 32 + kofs];
#pragma unroll
        for (int i = 0; i < 4; ++i)
#pragma unroll
            for (int j = 0; j < 4; ++j)
                acc[i][j] = __builtin_amdgcn_mfma_f32_16x16x32_bf16(av[i], bv[j], acc[i][j], 0, 0, 0);
    }

    const int r0 = blockIdx.y * 128 + wm * 64;
    const int c0 = blockIdx.x * 128 + wn * 64;
    const int lcol = lane & 15, lrow = (lane >> 4) << 2;
#pragma unroll
    for (int i = 0; i < 4; ++i)
#pragma unroll
        for (int j = 0; j < 4; ++j) {
            const int row = r0 + i * 16 + lrow;
            const int col = c0 + j * 16 + lcol;
#pragma unroll
            for (int r = 0; r < 4; ++r) {
                if constexpr (ATOMIC)
                    atomicAdd(&C[(long)(row + r) * ldc + col], acc[i][j][r]);
                else
                    storeC(&C[(long)(row + r) * ldc + col], acc[i][j][r]);
            }
        }
}

// ---------------------------------------------------------------------------
// 256x256 MFMA NT GEMM — ROUND-6 inner loop (single phase per BK=32 chunk,
// depth-3 counted-vmcnt pipeline, 4 LDS bufs, chunk-XOR swizzle). Proven
// 132 us / MfmaUtil 45% / 0 bank conflicts. STATS: fused sum/sumsq atomics.
// ---------------------------------------------------------------------------
template <typename TC, bool STATS>
__global__ __launch_bounds__(512, 2) void gemm_mfma_nt256(
    const bf16* __restrict__ A0, const bf16* __restrict__ B0, TC* __restrict__ C0,
    int K, int lda, int ldb, int ldc, long sA, long sB, long sC, float* __restrict__ red)
{
    extern __shared__ bf16 lds[];       // 4 bufs x (A 8192 + B 8192) elems = 128 KiB
    const int z = blockIdx.z;
    const bf16* A = A0 + (long)z * sA + (long)blockIdx.y * 256 * lda;
    const bf16* B = B0 + (long)z * sB + (long)blockIdx.x * 256 * ldb;
    TC*       C = C0 + (long)z * sC;

    const int t = threadIdx.x, lane = t & 63, w = t >> 6;
    const int wm = w >> 2, wn = w & 3;       // 2 x 4 wave grid
    const int lr = lane & 15, lg = lane >> 4;

    f32x4 acc[8][4] = {};
    const int KT = K >> 5;

    const int srow = t >> 2, spc = t & 3;    // stage: row-in-sweep, phys chunk
    auto STAGE = [&](int c) {
        bf16* base = lds + (c & 3) * 16384;
        const bf16* Ag = A + c * 32;
        const bf16* Bg = B + c * 32;
        int r0 = srow, r1 = srow + 128;
        int c0 = (spc ^ ((r0 >> 1) & 3)) << 3;
        int c1 = (spc ^ ((r1 >> 1) & 3)) << 3;
        gl2lds16(Ag + (long)r0 * lda + c0, base + w * 512);
        gl2lds16(Ag + (long)r1 * lda + c1, base + 4096 + w * 512);
        gl2lds16(Bg + (long)r0 * ldb + c0, base + 8192 + w * 512);
        gl2lds16(Bg + (long)r1 * ldb + c1, base + 12288 + w * 512);
    };

    if (KT > 0) STAGE(0);
    if (KT > 1) STAGE(1);
    if (KT > 2) STAGE(2);

    for (int c = 0; c < KT; ++c) {
        const int rem = KT - 1 - c;
        if (rem >= 2)      asm volatile("s_waitcnt vmcnt(8)" ::: "memory");
        else if (rem == 1) asm volatile("s_waitcnt vmcnt(4)" ::: "memory");
        else               asm volatile("s_waitcnt vmcnt(0)" ::: "memory");
        __builtin_amdgcn_s_barrier();
        asm volatile("" ::: "memory");       // keep this chunk's ds_reads below
        if (c + 3 < KT) STAGE(c + 3);

        const bf16* Ab = lds + (c & 3) * 16384;
        const bf16* Bb = Ab + 8192;
        bf16x8 bfrag[4], afrag[8];
#pragma unroll
        for (int j = 0; j < 4; ++j) {
            const int r = wn * 64 + j * 16 + lr;
            bfrag[j] = *(const bf16x8*)&Bb[r * 32 + ((lg ^ ((r >> 1) & 3)) << 3)];
        }
#pragma unroll
        for (int i = 0; i < 8; ++i) {
            const int r = wm * 128 + i * 16 + lr;
            afrag[i] = *(const bf16x8*)&Ab[r * 32 + ((lg ^ ((r >> 1) & 3)) << 3)];
        }
        __builtin_amdgcn_s_setprio(1);
#pragma unroll
        for (int i = 0; i < 8; ++i)
#pragma unroll
            for (int j = 0; j < 4; ++j)
                acc[i][j] = __builtin_amdgcn_mfma_f32_16x16x32_bf16(afrag[i], bfrag[j], acc[i][j], 0, 0, 0);
        __builtin_amdgcn_s_setprio(0);
    }

    const int r0 = blockIdx.y * 256 + wm * 128 + (lg << 2);
    const int c0 = blockIdx.x * 256 + wn * 64 + lr;
#pragma unroll
    for (int i = 0; i < 8; ++i)
#pragma unroll
        for (int j = 0; j < 4; ++j) {
#pragma unroll
            for (int rr = 0; rr < 4; ++rr)
                storeC(&C[(long)(r0 + i * 16 + rr) * ldc + (c0 + j * 16)], acc[i][j][rr]);
        }

    if constexpr (STATS) {
        float s1 = 0.f, s2 = 0.f;
#pragma unroll
        for (int i = 0; i < 8; ++i)
#pragma unroll
            for (int j = 0; j < 4; ++j)
#pragma unroll
                for (int rr = 0; rr < 4; ++rr) {
                    float v = acc[i][j][rr];
                    s1 += v; s2 += v * v;
                }
#pragma unroll
        for (int o = 32; o > 0; o >>= 1) { s1 += __shfl_xor(s1, o); s2 += __shfl_xor(s2, o); }
        __syncthreads();                      // LDS free now
        float* rb = (float*)lds;
        if (lane == 0) { rb[w] = s1; rb[8 + w] = s2; }
        __syncthreads();
        if (t == 0) {
            float a = 0.f, b = 0.f;
#pragma unroll
            for (int i = 0; i < 8; ++i) { a += rb[i]; b += rb[8 + i]; }
            atomicAdd(&red[z * 2], a);
            atomicAdd(&red[z * 2 + 1], b);
        }
    }
}

// ---------------------------------------------------------------------------
// prep (round-7 proven): emb->bf16 | 7 weights->bf16 | wo_u reorder | zero
// attnU | zero red2.  3521 blocks x 256.
// ---------------------------------------------------------------------------
__global__ __launch_bounds__(256) void prep(
    const float* __restrict__ emb,
    const float* w0, const float* w1, const float* w2, const float* w3,
    const float* w4, const float* w5, const float* w6,
    const float* __restrict__ wo_u,
    bf16* __restrict__ embB, bf16* __restrict__ wB, bf16* __restrict__ woUrB,
    float* __restrict__ attnU, float* __restrict__ red2)
{
    const int b = blockIdx.x;
    if (b < 2496) {
        const float* in;
        bf16* out;
        int i;
        if (b < 2048) {
            in = emb; out = embB;
            i = (b * 256 + threadIdx.x) * 8;
        } else {
            const int sub = b - 2048;
            const float* srcs[7] = {w0, w1, w2, w3, w4, w5, w6};
            in = srcs[sub >> 6];
            out = wB + (long)(sub >> 6) * 131072;
            i = ((sub & 63) * 256 + threadIdx.x) * 8;
        }
        float4 a = *(const float4*)(in + i);
        float4 c = *(const float4*)(in + i + 4);
        union { bf16 h[8]; uint4 u; } pk;
        pk.h[0] = __float2bfloat16(a.x); pk.h[1] = __float2bfloat16(a.y);
        pk.h[2] = __float2bfloat16(a.z); pk.h[3] = __float2bfloat16(a.w);
        pk.h[4] = __float2bfloat16(c.x); pk.h[5] = __float2bfloat16(c.y);
        pk.h[6] = __float2bfloat16(c.z); pk.h[7] = __float2bfloat16(c.w);
        *(uint4*)(out + i) = pk.u;
    } else if (b < 3008) {
        int i = (b - 2496) * 256 + threadIdx.x;   // 131072
        int j = i >> 10, col = i & 1023;
        int h = col >> 7, cc = col & 127;
        woUrB[i] = __float2bfloat16(wo_u[j * 1024 + cc * 8 + h]);
    } else if (b < 3520) {
        int i = ((b - 3008) * 256 + threadIdx.x) * 4;
        *(float4*)(attnU + i) = float4{0.f, 0.f, 0.f, 0.f};
    } else {
        if (threadIdx.x < 8) red2[threadIdx.x] = 0.f;
    }
}

// ---------------------------------------------------------------------------
// softmaxU_fused: per (b,h) block: instance-norm stats over 128x128 +
// row-softmax + TRANSPOSED bf16 output simUT[bh][d][c].
// Dynamic LDS: tile[128][129] f32 + rowinv[128] + rbuf[8] = 66592 B.
// ---------------------------------------------------------------------------
__global__ __launch_bounds__(256) void softmaxU_fused(const float* __restrict__ attnU,
                                                      bf16* __restrict__ simUT)
{
    extern __shared__ float sm[];
    float* tile = sm;                    // [128][129]
    float* rowinv = sm + 128 * 129;      // [128]
    float* rbuf = rowinv + 128;          // [8]
    const int bh = blockIdx.x;
    const float* p = attnU + (long)bh * 16384;
    const int t = threadIdx.x;

    float s1 = 0.f, s2 = 0.f;
    for (int i = t; i < 16384; i += 256) {
        float v = p[i];
        tile[(i >> 7) * 129 + (i & 127)] = v;
        s1 += v; s2 += v * v;
    }
#pragma unroll
    for (int o = 32; o > 0; o >>= 1) { s1 += __shfl_xor(s1, o); s2 += __shfl_xor(s2, o); }
    if ((t & 63) == 0) { rbuf[t >> 6] = s1; rbuf[4 + (t >> 6)] = s2; }
    __syncthreads();
    const float mu = (rbuf[0] + rbuf[1] + rbuf[2] + rbuf[3]) * (1.f / 16384.f);
    const float m2 = (rbuf[4] + rbuf[5] + rbuf[6] + rbuf[7]) * (1.f / 16384.f);
    const float rs = rsqrtf(m2 - mu * mu + 1e-5f);

    if (t < 128) {                       // row c = t; shift-invariance: softmax((x-mu)rs) = softmax((x-mx)rs)
        float* row = tile + t * 129;
        float mx = -3.0e38f;
        for (int d = 0; d < 128; ++d) mx = fmaxf(mx, row[d]);
        float s = 0.f;
        for (int d = 0; d < 128; ++d) { float e = expf((row[d] - mx) * rs); row[d] = e; s += e; }
        rowinv[t] = 1.f / s;
    }
    __syncthreads();
    // transposed write: thread t covers output elems [t*64, t*64+64): d = idx>>7, c = idx&127
    {
        const int d = t >> 1, ch = (t & 1) * 64;
        bf16* q = simUT + (long)bh * 16384 + d * 128 + ch;
        for (int i = 0; i < 64; i += 2) {
            float a = tile[(ch + i) * 129 + d] * rowinv[ch + i];
            float b = tile[(ch + i + 1) * 129 + d] * rowinv[ch + i + 1];
            union { bf16 h[2]; unsigned u; } pk;
            pk.h[0] = __float2bfloat16(a); pk.h[1] = __float2bfloat16(b);
            *(unsigned*)(q + i) = pk.u;
        }
    }
}

// ---------------------------------------------------------------------------
// sm2_rowstats: per row r=(b*1024+c) of attn2F: raw row max + 1/sum(exp((x-mx)*rs)).
// ---------------------------------------------------------------------------
__global__ __launch_bounds__(256) void sm2_rowstats(const float* __restrict__ attn2,
                                                    const float* __restrict__ red,
                                                    float* __restrict__ rowstat)
{
    const int r = blockIdx.x;
    const int b = r >> 10;
    const float inv = 1.f / 4194304.f;
    const float mu = red[b * 2] * inv;
    const float var = red[b * 2 + 1] * inv - mu * mu;
    const float rs = rsqrtf(var + 1e-5f);
    const float* p = attn2 + (long)r * 4096;
    const int t = threadIdx.x;
    float v[16];
    float mx = -3.0e38f;
#pragma unroll
    for (int i = 0; i < 16; ++i) { v[i] = p[i * 256 + t]; mx = fmaxf(mx, v[i]); }
#pragma unroll
    for (int o = 32; o > 0; o >>= 1) mx = fmaxf(mx, __shfl_xor(mx, o));
    __shared__ float sm[4], ss[4];
    if ((t & 63) == 0) sm[t >> 6] = mx;
    __syncthreads();
    mx = fmaxf(fmaxf(sm[0], sm[1]), fmaxf(sm[2], sm[3]));
    float s = 0.f;
#pragma unroll
    for (int i = 0; i < 16; ++i) s += expf((v[i] - mx) * rs);
#pragma unroll
    for (int o = 32; o > 0; o >>= 1) s += __shfl_xor(s, o);
    if ((t & 63) == 0) ss[t >> 6] = s;
    __syncthreads();
    if (t == 0) {
        s = ss[0] + ss[1] + ss[2] + ss[3];
        rowstat[r * 2] = mx;
        rowstat[r * 2 + 1] = 1.f / s;
    }
}

// ---------------------------------------------------------------------------
// sm2_transpose: tile-apply + transpose. grid (32 dt, 8 ct, 4 b), 256 thr.
// reads attn2F[b][ct*128+c][dt*128+d], writes sim2T[b][dt*128+d][ct*128+c] bf16.
// Dynamic LDS tile[128][129] f32 = 66048 B.
// ---------------------------------------------------------------------------
__global__ __launch_bounds__(256) void sm2_transpose(const float* __restrict__ attn2,
                                                     const float* __restrict__ red,
                                                     const float* __restrict__ rowstat,
                                                     bf16* __restrict__ sim2T)
{
    extern __shared__ float tile[];      // [128][129]
    const int dt = blockIdx.x, ct = blockIdx.y, b = blockIdx.z;
    const float inv = 1.f / 4194304.f;
    const float mu = red[b * 2] * inv;
    const float var = red[b * 2 + 1] * inv - mu * mu;
    const float rs = rsqrtf(var + 1e-5f);
    const int t = threadIdx.x;
    const float* in = attn2 + (long)b * 4194304 + (long)(ct * 128) * 4096 + dt * 128;
    {
        const int c = t >> 1, dh = (t & 1) * 64;
        const float2 st = *(const float2*)&rowstat[(b * 1024 + ct * 128 + c) * 2];
        const float mx = st.x, is = st.y;
        const float* src = in + (long)c * 4096 + dh;
        float* dst = tile + c * 129 + dh;
        for (int i = 0; i < 64; i += 4) {
            float4 x = *(const float4*)(src + i);
            dst[i]     = expf((x.x - mx) * rs) * is;
            dst[i + 1] = expf((x.y - mx) * rs) * is;
            dst[i + 2] = expf((x.z - mx) * rs) * is;
            dst[i + 3] = expf((x.w - mx) * rs) * is;
        }
    }
    __syncthreads();
    {
        const int d = t >> 1, ch = (t & 1) * 64;
        bf16* q = sim2T + (long)b * 4194304 + (long)(dt * 128 + d) * 1024 + ct * 128 + ch;
        for (int i = 0; i < 64; i += 2) {
            union { bf16 h[2]; unsigned u; } pk;
            pk.h[0] = __float2bfloat16(tile[(ch + i) * 129 + d]);
            pk.h[1] = __float2bfloat16(tile[(ch + i + 1) * 129 + d]);
            *(unsigned*)(q + i) = pk.u;
        }
    }
}

// ---------------------------------------------------------------------------
// reduce4: out[i] = sum_{s<4} partial[s][i]; lower half from pOl, upper from pOu.
// ---------------------------------------------------------------------------
__global__ __launch_bounds__(256) void reduce4(const float* __restrict__ pOl,
                                               const float* __restrict__ pOu,
                                               float* __restrict__ out)
{
    const long i = ((long)blockIdx.x * 256 + threadIdx.x) * 4;
    const float* src = (i < 2097152) ? (pOl + i) : (pOu + (i - 2097152));
    f32x4 a = *(const f32x4*)src;
    a += *(const f32x4*)(src + 2097152);
    a += *(const f32x4*)(src + 4194304);
    a += *(const f32x4*)(src + 6291456);
    *(f32x4*)(out + i) = a;
}

// ---------------------------------------------------------------------------
extern "C" void kernel_launch(void* const* d_in, const int* in_sizes, int n_in,
                              void* d_out, int out_size, void* d_ws, size_t ws_size,
                              hipStream_t stream)
{
    const float* emb   = (const float*)d_in[0];
    const float* wq_uu = (const float*)d_in[1];
    const float* wk_uu = (const float*)d_in[2];
    const float* wv_uu = (const float*)d_in[3];
    const float* wq_lu = (const float*)d_in[4];
    const float* wk_lu = (const float*)d_in[5];
    const float* wv_lu = (const float*)d_in[6];
    const float* wo_u  = (const float*)d_in[7];
    const float* wo_l  = (const float*)d_in[8];
    float* out = (float*)d_out;

    hipFuncSetAttribute(reinterpret_cast<const void*>(&gemm_mfma_nt256<float, true>),
                        hipFuncAttributeMaxDynamicSharedMemorySize, 131072);
    hipFuncSetAttribute(reinterpret_cast<const void*>(&softmaxU_fused),
                        hipFuncAttributeMaxDynamicSharedMemorySize, 66592);
    hipFuncSetAttribute(reinterpret_cast<const void*>(&sm2_transpose),
                        hipFuncAttributeMaxDynamicSharedMemorySize, 66048);

    // ---- workspace plan (~152 MB), U = 16,777,216 bf16 elems ----
    const long U = 16777216;
    bf16*  ws0    = (bf16*)d_ws;
    bf16*  slot0  = ws0;                   // QuT -> QlT -> sim2T -> pOl(f32)
    bf16*  slot1  = ws0 + U;               // KuT -> K2T -> V2
    float* attn2F = (float*)(ws0 + 2 * U); // 16.7M f32: attnU | attn2 | VuB(bf16)+pOu(f32)
    float* attnU  = attn2F;
    bf16*  VuB    = (bf16*)attn2F;         // [0,32MB) after sm2 passes
    float* pOu    = attn2F + 8388608;      // [32,64MB) f32 partials
    float* pOl    = (float*)slot0;         // after W2l consumed sim2T
    bf16*  sim2T  = slot0;
    bf16*  embB   = ws0 + 4 * U;           // 4,194,304
    bf16*  wB     = embB + 4194304;        // 7 x 131072: wq_uu wk_uu wq_lu wk_lu wv_uu wv_lu wo_l
    bf16*  wqUU  = wB;
    bf16*  wqLU  = wB + 262144;
    bf16*  wvUU  = wB + 524288;
    bf16*  wvLU  = wB + 655360;
    bf16*  woLB  = wB + 786432;
    bf16*  woUrB = wB + 917504;            // 131072
    bf16*  simUT = wB + 1048576;           // 524288 (32 x 128 x 128)
    bf16*  W2uB  = wB + 1572864;           // 524288 (4 x 8 x 128 x 128 -> [b][j][h*128+d])
    bf16*  W2lB  = wB + 2097152;           // 2097152 (4 x 128 x 4096)
    float* statsF = (float*)(wB + 4194304);
    float* red2   = statsF;                // 8
    float* rowstat = statsF + 8;           // 8192

    bf16* embB_l = embB;                   // [4][4096][128]
    bf16* embB_u = embB + 2097152;

    dim3 blk(256);

    // 1. setup
    prep<<<dim3(3521), blk, 0, stream>>>(
        emb, wq_uu, wk_uu, wq_lu, wk_lu, wv_uu, wv_lu, wo_l, wo_u,
        embB, wB, woUrB, attnU, red2);

    // 2. projU: z=(q*4+b): QuT->slot0, KuT->slot1   [o=1024 rows][n=4096]
    gemm_mfma_nt<bf16, false><<<dim3(32, 8, 8), blk, 0, stream>>>(
        wqUU, embB_u, slot0, 128, 128, 128, 4096,
        4, 131072, 0, 0, 524288, 16777216, 4194304);

    // 3. attnU K-split x8 atomic: z=(bh*8+kc)
    gemm_mfma_nt<float, true><<<dim3(1, 1, 256), blk, 0, stream>>>(
        slot0, slot1, attnU, 512, 4096, 4096, 128,
        8, 524288, 512, 524288, 512, 16384, 0);

    // 4. fused upper stats+softmax+transpose -> simUT[bh][d][c]
    softmaxU_fused<<<dim3(32), blk, 66592, stream>>>(attnU, simUT);

    // 5. projL: z=(q*4+b): QlT->slot0 (from emb_l), K2T->slot1 (from emb_u)
    gemm_mfma_nt<bf16, false><<<dim3(32, 8, 8), blk, 0, stream>>>(
        wqLU, embB_l, slot0, 128, 128, 128, 4096,
        4, 131072, 0, 2097152, 524288, 16777216, 4194304);

    // 6. attn2 (nt256, round-6 loop) + fused per-b stats
    gemm_mfma_nt256<float, true><<<dim3(16, 4, 4), dim3(512), 131072, stream>>>(
        slot0, slot1, attn2F, 4096, 4096, 4096, 4096,
        4194304, 0, 4194304, red2);

    // 7-8. lower softmax: rowstats then transpose-apply -> sim2T (slot0; QlT dead)
    sm2_rowstats<<<dim3(4096), blk, 0, stream>>>(attn2F, red2, rowstat);
    sm2_transpose<<<dim3(32, 8, 4), blk, 66048, stream>>>(attn2F, red2, rowstat, sim2T);

    // 9. V2[n][bp*1024+o] -> slot1 (K2T dead)
    gemm_mfma_nt<bf16, false><<<dim3(8, 32, 4), blk, 0, stream>>>(
        embB_u, wvLU, slot1, 128, 128, 128, 4096, 1, 524288, 0, 0, 0, 1024, 0);

    // 10. Vu[b][n][1024] -> VuB (attn2F[0,32MB); attn2 dead after sm2 passes)
    gemm_mfma_nt<bf16, false><<<dim3(8, 32, 4), blk, 0, stream>>>(
        embB_u, wvUU, VuB, 128, 128, 128, 1024, 1, 524288, 0, 0, 0, 4194304, 0);

    // 11. W2u[bh][j][d] = sum_c woUr[j][h*128+c] * simUT[bh][d][c]  (z=(b*8+h))
    gemm_mfma_nt<bf16, false><<<dim3(1, 1, 32), blk, 0, stream>>>(
        woUrB, simUT, W2uB, 128, 1024, 128, 1024,
        8, 0, 128, 131072, 16384, 131072, 128);

    // 12. W2l[b][j][d] = sum_c wo_l[j][c] * sim2T[b][d][c]  (z=b)
    gemm_mfma_nt<bf16, false><<<dim3(32, 1, 4), blk, 0, stream>>>(
        woLB, sim2T, W2lB, 1024, 1024, 1024, 4096,
        1, 0, 0, 4194304, 0, 524288, 0);

    // 13. O_u' partials: z=(s*4+b): pOu[s][b][n][j] = sum_{k in s-th quarter of 1024} Vu*W2u
    gemm_mfma_nt<float, false><<<dim3(1, 32, 16), blk, 0, stream>>>(
        VuB, W2uB, pOu, 256, 1024, 1024, 128,
        4, 256, 4194304, 256, 131072, 2097152, 524288);

    // 14. O_l' partials: z=(s*4+b): pOl[s][b][n][j] = sum_{d in s-th quarter of 4096} V2*W2l
    gemm_mfma_nt<float, false><<<dim3(1, 32, 16), blk, 0, stream>>>(
        slot1, W2lB, pOl, 1024, 4096, 4096, 128,
        4, 1024, 0, 1024, 524288, 2097152, 524288);

    // 15. out = sum of 4 partials (lower | upper)
    reduce4<<<dim3(4096), blk, 0, stream>>>(pOl, pOu, out);
}